// Round 3
// baseline (1265.052 us; speedup 1.0000x reference)
//
#include <hip/hip_runtime.h>

#define N_NODES 100000
#define N_EDGES 800000
#define HID 64
#define NGRAPH 64
#define OUTC 2
#define BN_EPS 1e-5f
#define NSCAN_BLK ((N_NODES + 255) / 256)   // 391
#define GEMM_BLK ((N_NODES + 63) / 64)      // 1563
#define POOL_SUB 16

// ---------------------------------------------------------------------------
// GEMM: Y[n,64] = T(X)[n,64] @ W[64,64] (+bias) (opt row-scale by dinv)
// T(X) = optional per-column BN (scale/shift) + optional ReLU, fused on load.
// IN_MODE: 0 = identity, 1 = BN, 2 = BN + ReLU
// STATS: emit per-block column sum/sumsq partials of the (biased) output.
// ---------------------------------------------------------------------------
template <int IN_MODE, bool ADD_BIAS, bool ROW_SCALE, bool STATS>
__global__ __launch_bounds__(256) void k_gemm(const float* __restrict__ X,
                                              const float* __restrict__ W,
                                              const float* __restrict__ bias,
                                              const float* __restrict__ dinv,
                                              const float* __restrict__ scsh,
                                              float* __restrict__ Y,
                                              float* __restrict__ partial, int n) {
    __shared__ float sW[64][64];   // [k][c]
    __shared__ float sX[64][68];   // rows 16B-aligned; 4-row stride = 16 banks
    const int tid  = threadIdx.x;
    const int row0 = blockIdx.x * 64;

    {   // load W (4096 floats) via float4
        const float4* Wv  = reinterpret_cast<const float4*>(W);
        float4*       sWv = reinterpret_cast<float4*>(&sW[0][0]);
        #pragma unroll
        for (int i = tid; i < 1024; i += 256) sWv[i] = Wv[i];
    }
    // load X tile (64x64) via float4 with fused BN/ReLU transform
    #pragma unroll
    for (int f = tid; f < 1024; f += 256) {
        int r = f >> 4, c4 = (f & 15) << 2;
        float4 v = make_float4(0.f, 0.f, 0.f, 0.f);
        if (row0 + r < n)
            v = *reinterpret_cast<const float4*>(&X[(size_t)(row0 + r) * HID + c4]);
        if (IN_MODE >= 1) {
            float4 sc = *reinterpret_cast<const float4*>(&scsh[c4]);
            float4 sh = *reinterpret_cast<const float4*>(&scsh[64 + c4]);
            v.x = v.x * sc.x + sh.x; v.y = v.y * sc.y + sh.y;
            v.z = v.z * sc.z + sh.z; v.w = v.w * sc.w + sh.w;
            if (IN_MODE == 2) {
                v.x = fmaxf(v.x, 0.f); v.y = fmaxf(v.y, 0.f);
                v.z = fmaxf(v.z, 0.f); v.w = fmaxf(v.w, 0.f);
            }
        }
        sX[r][c4 + 0] = v.x; sX[r][c4 + 1] = v.y;
        sX[r][c4 + 2] = v.z; sX[r][c4 + 3] = v.w;
    }
    __syncthreads();

    const int tr = tid >> 4;   // output rows tr*4..tr*4+3
    const int tc = tid & 15;   // output cols tc*4..tc*4+3
    float4 acc[4];
    #pragma unroll
    for (int i = 0; i < 4; ++i) acc[i] = make_float4(0.f, 0.f, 0.f, 0.f);

    const float4* sX4 = reinterpret_cast<const float4*>(&sX[0][0]);  // row stride 17
    #pragma unroll
    for (int k0 = 0; k0 < 64; k0 += 4) {
        float4 w0 = *reinterpret_cast<const float4*>(&sW[k0 + 0][tc << 2]);
        float4 w1 = *reinterpret_cast<const float4*>(&sW[k0 + 1][tc << 2]);
        float4 w2 = *reinterpret_cast<const float4*>(&sW[k0 + 2][tc << 2]);
        float4 w3 = *reinterpret_cast<const float4*>(&sW[k0 + 3][tc << 2]);
        #pragma unroll
        for (int i = 0; i < 4; ++i) {
            float4 a = sX4[((tr << 2) + i) * 17 + (k0 >> 2)];
            acc[i].x += a.x * w0.x + a.y * w1.x + a.z * w2.x + a.w * w3.x;
            acc[i].y += a.x * w0.y + a.y * w1.y + a.z * w2.y + a.w * w3.y;
            acc[i].z += a.x * w0.z + a.y * w1.z + a.z * w2.z + a.w * w3.z;
            acc[i].w += a.x * w0.w + a.y * w1.w + a.z * w2.w + a.w * w3.w;
        }
    }

    float4 bb = make_float4(0.f, 0.f, 0.f, 0.f);
    if (ADD_BIAS) bb = *reinterpret_cast<const float4*>(&bias[tc << 2]);

    float4 o[4];
    bool valid[4];
    #pragma unroll
    for (int i = 0; i < 4; ++i) {
        int r = row0 + (tr << 2) + i;
        valid[i] = (r < n);
        float s = ROW_SCALE ? (valid[i] ? dinv[r] : 1.f) : 1.f;
        o[i].x = acc[i].x * s + bb.x;
        o[i].y = acc[i].y * s + bb.y;
        o[i].z = acc[i].z * s + bb.z;
        o[i].w = acc[i].w * s + bb.w;
        if (valid[i])
            *reinterpret_cast<float4*>(&Y[(size_t)r * HID + (tc << 2)]) = o[i];
    }

    if (STATS) {
        // per-thread column sums over its 4 rows, reduced via reused sX LDS
        float sx = 0.f, sy = 0.f, sz = 0.f, sw = 0.f;
        float qx = 0.f, qy = 0.f, qz = 0.f, qw = 0.f;
        #pragma unroll
        for (int i = 0; i < 4; ++i) {
            if (valid[i]) {
                sx += o[i].x; qx += o[i].x * o[i].x;
                sy += o[i].y; qy += o[i].y * o[i].y;
                sz += o[i].z; qz += o[i].z * o[i].z;
                sw += o[i].w; qw += o[i].w * o[i].w;
            }
        }
        __syncthreads();                       // done reading sX; safe to reuse
        float* st = &sX[0][0];                 // [0..1023]=sum, [1024..2047]=sq
        int cbase = (tc << 2);
        st[tr * 64 + cbase + 0] = sx; st[1024 + tr * 64 + cbase + 0] = qx;
        st[tr * 64 + cbase + 1] = sy; st[1024 + tr * 64 + cbase + 1] = qy;
        st[tr * 64 + cbase + 2] = sz; st[1024 + tr * 64 + cbase + 2] = qz;
        st[tr * 64 + cbase + 3] = sw; st[1024 + tr * 64 + cbase + 3] = qw;
        __syncthreads();
        if (tid < 64) {
            float S = 0.f, Q = 0.f;
            #pragma unroll
            for (int t = 0; t < 16; ++t) {
                S += st[t * 64 + tid];
                Q += st[1024 + t * 64 + tid];
            }
            partial[blockIdx.x * 128 + tid]      = S;
            partial[blockIdx.x * 128 + 64 + tid] = Q;
        }
    }
}

// Reduce per-block partials -> scale/shift. One block per column.
__global__ __launch_bounds__(256) void k_statsfin(const float* __restrict__ partial,
                                                  const float* __restrict__ g,
                                                  const float* __restrict__ beta,
                                                  float* __restrict__ scsh, int n) {
    int c = blockIdx.x, t = threadIdx.x;
    float S = 0.f, Q = 0.f;
    for (int b = t; b < GEMM_BLK; b += 256) {
        S += partial[b * 128 + c];
        Q += partial[b * 128 + 64 + c];
    }
    __shared__ float ss[256], sq[256];
    ss[t] = S; sq[t] = Q;
    __syncthreads();
    for (int off = 128; off > 0; off >>= 1) {
        if (t < off) { ss[t] += ss[t + off]; sq[t] += sq[t + off]; }
        __syncthreads();
    }
    if (t == 0) {
        float nf = (float)n;
        float m  = ss[0] / nf;
        float v  = sq[0] / nf - m * m;
        float sc = rsqrtf(v + BN_EPS) * g[c];
        scsh[c]      = sc;
        scsh[64 + c] = beta[c] - m * sc;
    }
}

// ---------------------------------------------------------------------------
// CSR build: degree, exclusive scan, fill (atomicSub countdown into indeg)
// ---------------------------------------------------------------------------
__global__ __launch_bounds__(256) void k_deg(const int* __restrict__ dst,
                                             int* __restrict__ indeg) {
    int e = blockIdx.x * 256 + threadIdx.x;
    if (e < N_EDGES) atomicAdd(&indeg[dst[e]], 1);
}

__global__ __launch_bounds__(256) void k_scanpart(const int* __restrict__ indeg,
                                                  int* __restrict__ bsum) {
    __shared__ int s[256];
    int i = blockIdx.x * 256 + threadIdx.x;
    s[threadIdx.x] = (i < N_NODES) ? indeg[i] : 0;
    __syncthreads();
    for (int off = 128; off > 0; off >>= 1) {
        if (threadIdx.x < off) s[threadIdx.x] += s[threadIdx.x + off];
        __syncthreads();
    }
    if (threadIdx.x == 0) bsum[blockIdx.x] = s[0];
}

__global__ __launch_bounds__(512) void k_scanmid(int* __restrict__ bsum, int nblk) {
    __shared__ int s[512];
    int t = threadIdx.x;
    int v = (t < nblk) ? bsum[t] : 0;
    s[t] = v;
    __syncthreads();
    for (int off = 1; off < 512; off <<= 1) {
        int x = (t >= off) ? s[t - off] : 0;
        __syncthreads();
        s[t] += x;
        __syncthreads();
    }
    if (t < nblk) bsum[t] = s[t] - v;   // exclusive
}

__global__ __launch_bounds__(256) void k_scanfinal(const int* __restrict__ indeg,
                                                   const int* __restrict__ bsum,
                                                   int* __restrict__ rowptr) {
    __shared__ int s[256];
    int t = threadIdx.x;
    int i = blockIdx.x * 256 + t;
    int v = (i < N_NODES) ? indeg[i] : 0;
    s[t] = v;
    __syncthreads();
    for (int off = 1; off < 256; off <<= 1) {
        int x = (t >= off) ? s[t - off] : 0;
        __syncthreads();
        s[t] += x;
        __syncthreads();
    }
    if (i < N_NODES) rowptr[i] = bsum[blockIdx.x] + s[t] - v;
    if (i == 0) rowptr[N_NODES] = N_EDGES;
}

__global__ __launch_bounds__(256) void k_dinv(const int* __restrict__ indeg,
                                              float* __restrict__ dinv) {
    int i = blockIdx.x * 256 + threadIdx.x;
    if (i < N_NODES) dinv[i] = rsqrtf((float)indeg[i] + 1.f);
}

__global__ __launch_bounds__(256) void k_fill(const int* __restrict__ src,
                                              const int* __restrict__ dst,
                                              const int* __restrict__ rowptr,
                                              int* __restrict__ indeg,
                                              int* __restrict__ colidx) {
    int e = blockIdx.x * 256 + threadIdx.x;
    if (e >= N_EDGES) return;
    int d = dst[e];
    int pos = rowptr[d] + (atomicSub(&indeg[d], 1) - 1);
    colidx[pos] = src[e];
}

// ---------------------------------------------------------------------------
// Fused gather + conv finalize: one wave per dst node.
// Out[d] = (sum_{s in N(d)} HW[s] + HW[d]) * dinv[d] + bias + T(Hin[d]), opt ReLU
// ---------------------------------------------------------------------------
template <int IN_MODE, bool RELU>
__global__ __launch_bounds__(256) void k_gather(const int* __restrict__ rowptr,
                                                const int* __restrict__ colidx,
                                                const float* __restrict__ HW,
                                                const float* __restrict__ Hin,
                                                const float* __restrict__ dinv,
                                                const float* __restrict__ bias,
                                                const float* __restrict__ scsh,
                                                float* __restrict__ Out) {
    int d = blockIdx.x * 4 + (threadIdx.x >> 6);
    if (d >= N_NODES) return;
    int lane = threadIdx.x & 63;
    int j0 = rowptr[d], j1 = rowptr[d + 1];
    float acc = HW[(size_t)d * HID + lane];          // self-loop term
    for (int j = j0; j < j1; ++j) {
        int s = colidx[j];
        acc += HW[(size_t)s * HID + lane];
    }
    float hin = Hin[(size_t)d * HID + lane];
    if (IN_MODE == 1) hin = hin * scsh[lane] + scsh[64 + lane];
    float v = acc * dinv[d] + bias[lane] + hin;
    if (RELU) v = fmaxf(v, 0.f);
    Out[(size_t)d * HID + lane] = v;
}

// ---------------------------------------------------------------------------
// Two-stage segment-mean pool over sorted batch + fused final BN
// ---------------------------------------------------------------------------
__device__ __forceinline__ int lowerb(const int* __restrict__ b, int n, int v) {
    int lo = 0, hi = n;
    while (lo < hi) { int m = (lo + hi) >> 1; if (b[m] < v) lo = m + 1; else hi = m; }
    return lo;
}

__global__ __launch_bounds__(256) void k_pool1(const float* __restrict__ Y,
                                               const int* __restrict__ batch,
                                               float* __restrict__ partial2) {
    int g  = blockIdx.x >> 4;
    int sb = blockIdx.x & 15;
    int tid = threadIdx.x, col = tid & 63, rg = tid >> 6;
    int lo = lowerb(batch, N_NODES, g);
    int hi = lowerb(batch, N_NODES, g + 1);
    int cnt = hi - lo;
    int st = lo + (int)(((long long)cnt * sb) >> 4);
    int en = lo + (int)(((long long)cnt * (sb + 1)) >> 4);
    float s = 0.f;
    for (int r = st + rg; r < en; r += 4) s += Y[(size_t)r * HID + col];
    __shared__ float ls[4][64];
    ls[rg][col] = s;
    __syncthreads();
    if (tid < 64)
        partial2[(size_t)blockIdx.x * 64 + tid] =
            ls[0][tid] + ls[1][tid] + ls[2][tid] + ls[3][tid];
}

__global__ __launch_bounds__(64) void k_pool2(const float* __restrict__ partial2,
                                              const int* __restrict__ batch,
                                              const float* __restrict__ scsh,
                                              float* __restrict__ pooled) {
    int g = blockIdx.x, c = threadIdx.x;
    float S = 0.f;
    #pragma unroll
    for (int sb = 0; sb < POOL_SUB; ++sb)
        S += partial2[(size_t)(g * POOL_SUB + sb) * 64 + c];
    int lo = lowerb(batch, N_NODES, g);
    int hi = lowerb(batch, N_NODES, g + 1);
    int cnt = hi - lo;
    float out = 0.f;
    if (cnt > 0) {
        float mean = S / (float)cnt;
        out = mean * scsh[c] + scsh[64 + c];
    }
    pooled[g * 64 + c] = out;
}

// ---------------------------------------------------------------------------
// Final head
// ---------------------------------------------------------------------------
__global__ __launch_bounds__(256) void k_final(const float* __restrict__ pooled,
                                               const float* __restrict__ W0,
                                               const float* __restrict__ b0,
                                               const float* __restrict__ W1,
                                               const float* __restrict__ b1,
                                               const float* __restrict__ W2,
                                               const float* __restrict__ b2,
                                               float* __restrict__ out) {
    __shared__ float P[64][65];
    __shared__ float Z[64][65];
    int tid = threadIdx.x;
    for (int i = tid; i < NGRAPH * HID; i += 256) P[i >> 6][i & 63] = pooled[i];
    __syncthreads();
    for (int t = 0; t < 16; ++t) {
        int o = tid + 256 * t; int r = o >> 6, c = o & 63;
        float acc = b0[c];
        #pragma unroll 8
        for (int k = 0; k < 64; ++k) acc += P[r][k] * W0[k * 64 + c];
        Z[r][c] = fmaxf(acc, 0.f);
    }
    __syncthreads();
    for (int t = 0; t < 16; ++t) {
        int o = tid + 256 * t; int r = o >> 6, c = o & 63;
        float acc = b1[c];
        #pragma unroll 8
        for (int k = 0; k < 64; ++k) acc += Z[r][k] * W1[k * 64 + c];
        P[r][c] = fmaxf(acc, 0.f);
    }
    __syncthreads();
    if (tid < NGRAPH * OUTC) {
        int r = tid >> 1, c = tid & 1;
        float acc = b2[c];
        #pragma unroll 8
        for (int k = 0; k < 64; ++k) acc += P[r][k] * W2[k * OUTC + c];
        out[tid] = acc;
    }
}

// ---------------------------------------------------------------------------
extern "C" void kernel_launch(void* const* d_in, const int* in_sizes, int n_in,
                              void* d_out, int out_size, void* d_ws, size_t ws_size,
                              hipStream_t stream) {
    const float* x        = (const float*)d_in[0];
    const int*   ei       = (const int*)d_in[1];
    const int*   batch    = (const int*)d_in[2];
    const float* pre_W    = (const float*)d_in[3];
    const float* pre_b    = (const float*)d_in[4];
    const float* pre_g    = (const float*)d_in[5];
    const float* pre_beta = (const float*)d_in[6];
    const float* conv_W   = (const float*)d_in[7];
    const float* conv_b   = (const float*)d_in[8];
    const float* post_W   = (const float*)d_in[9];
    const float* post_b   = (const float*)d_in[10];
    const float* post_g   = (const float*)d_in[11];
    const float* post_beta= (const float*)d_in[12];
    const float* fW0 = (const float*)d_in[13];
    const float* fb0 = (const float*)d_in[14];
    const float* fW1 = (const float*)d_in[15];
    const float* fb1 = (const float*)d_in[16];
    const float* fW2 = (const float*)d_in[17];
    const float* fb2 = (const float*)d_in[18];
    float* out = (float*)d_out;

    const size_t NH = (size_t)N_NODES * HID;
    float* ws       = (float*)d_ws;
    float* A        = ws;
    float* B        = A + NH;
    float* C        = B + NH;
    float* dinv     = C + NH;                         // N
    float* partial  = dinv + N_NODES;                 // GEMM_BLK*128
    float* scsh     = partial + (size_t)GEMM_BLK*128; // 6 slots of 128
    float* pooled   = scsh + 6 * 128;                 // 64*64
    float* partial2 = pooled + NGRAPH * HID;          // 1024*64
    int*   indeg    = (int*)(partial2 + NGRAPH * POOL_SUB * 64);
    int*   rowptr   = indeg + N_NODES;                // N+1
    int*   colidx   = rowptr + N_NODES + 1;           // E
    int*   bsum     = colidx + N_EDGES;               // NSCAN_BLK

    const int* srcp = ei;
    const int* dstp = ei + N_EDGES;

    const int gEdge  = (N_EDGES + 255) / 256;
    const int gNode  = (N_NODES + 255) / 256;
    const int gNode4 = (N_NODES + 3) / 4;

    // ---- CSR build ----
    hipMemsetAsync(indeg, 0, N_NODES * sizeof(int), stream);
    k_deg<<<gEdge, 256, 0, stream>>>(dstp, indeg);
    k_scanpart<<<NSCAN_BLK, 256, 0, stream>>>(indeg, bsum);
    k_scanmid<<<1, 512, 0, stream>>>(bsum, NSCAN_BLK);
    k_scanfinal<<<NSCAN_BLK, 256, 0, stream>>>(indeg, bsum, rowptr);
    k_dinv<<<gNode, 256, 0, stream>>>(indeg, dinv);
    k_fill<<<gEdge, 256, 0, stream>>>(srcp, dstp, rowptr, indeg, colidx);

    // ---- pre-processing: GEMM(+fused prev BN/ReLU, +stats) ----
    k_gemm<0, true, false, true><<<GEMM_BLK, 256, 0, stream>>>(x, pre_W, pre_b, nullptr, nullptr, A, partial, N_NODES);
    k_statsfin<<<64, 256, 0, stream>>>(partial, pre_g, pre_beta, scsh + 0 * 128, N_NODES);

    k_gemm<2, true, false, true><<<GEMM_BLK, 256, 0, stream>>>(A, pre_W + 4096, pre_b + 64, nullptr, scsh + 0 * 128, B, partial, N_NODES);
    k_statsfin<<<64, 256, 0, stream>>>(partial, pre_g + 64, pre_beta + 64, scsh + 1 * 128, N_NODES);

    k_gemm<2, true, false, true><<<GEMM_BLK, 256, 0, stream>>>(B, pre_W + 2 * 4096, pre_b + 128, nullptr, scsh + 1 * 128, A, partial, N_NODES);
    k_statsfin<<<64, 256, 0, stream>>>(partial, pre_g + 128, pre_beta + 128, scsh + 2 * 128, N_NODES);

    // ---- GCNConv stack ----
    for (int i = 0; i < 6; ++i) {
        const float* in = (i & 1) ? C : A;
        float*     outb = (i & 1) ? A : C;
        const float* Wl = conv_W + i * 4096;
        const float* bl = conv_b + i * 64;
        if (i == 0)
            k_gemm<1, false, true, false><<<GEMM_BLK, 256, 0, stream>>>(in, Wl, nullptr, dinv, scsh + 2 * 128, B, nullptr, N_NODES);
        else
            k_gemm<0, false, true, false><<<GEMM_BLK, 256, 0, stream>>>(in, Wl, nullptr, dinv, nullptr, B, nullptr, N_NODES);

        if (i == 0)
            k_gather<1, true ><<<gNode4, 256, 0, stream>>>(rowptr, colidx, B, in, dinv, bl, scsh + 2 * 128, outb);
        else if (i != 5)
            k_gather<0, true ><<<gNode4, 256, 0, stream>>>(rowptr, colidx, B, in, dinv, bl, nullptr, outb);
        else
            k_gather<0, false><<<gNode4, 256, 0, stream>>>(rowptr, colidx, B, in, dinv, bl, nullptr, outb);
    }
    // conv output in A

    // ---- post-processing ----
    k_gemm<0, true, false, true><<<GEMM_BLK, 256, 0, stream>>>(A, post_W, post_b, nullptr, nullptr, B, partial, N_NODES);
    k_statsfin<<<64, 256, 0, stream>>>(partial, post_g, post_beta, scsh + 3 * 128, N_NODES);

    k_gemm<2, true, false, true><<<GEMM_BLK, 256, 0, stream>>>(B, post_W + 4096, post_b + 64, nullptr, scsh + 3 * 128, C, partial, N_NODES);
    k_statsfin<<<64, 256, 0, stream>>>(partial, post_g + 64, post_beta + 64, scsh + 4 * 128, N_NODES);

    k_gemm<2, true, false, true><<<GEMM_BLK, 256, 0, stream>>>(C, post_W + 2 * 4096, post_b + 128, nullptr, scsh + 4 * 128, B, partial, N_NODES);
    k_statsfin<<<64, 256, 0, stream>>>(partial, post_g + 128, post_beta + 128, scsh + 5 * 128, N_NODES);

    // ---- pool (two-stage segment mean, fused final BN) + head ----
    k_pool1<<<NGRAPH * POOL_SUB, 256, 0, stream>>>(B, batch, partial2);
    k_pool2<<<NGRAPH, 64, 0, stream>>>(partial2, batch, scsh + 5 * 128, pooled);
    k_final<<<1, 256, 0, stream>>>(pooled, fW0, fb0, fW1, fb1, fW2, fb2, out);
}

// Round 4
// 703.647 us; speedup vs baseline: 1.7979x; 1.7979x over previous
//
#include <hip/hip_runtime.h>

#define N_NODES 100000
#define N_EDGES 800000
#define HID 64
#define NGRAPH 64
#define OUTC 2
#define BN_EPS 1e-5f
#define NSCAN_BLK ((N_NODES + 255) / 256)   // 391
#define GEMM_BLK ((N_NODES + 63) / 64)      // 1563
#define POOL_SUB 16

// ---------------------------------------------------------------------------
// GEMM: Y[n,64] = T(X)[n,64] @ W[64,64] (+bias) (opt row-scale by dinv)
// T(X) = optional per-column BN (scale/shift) + optional ReLU, fused on load.
// IN_MODE: 0 = identity, 1 = BN, 2 = BN + ReLU
// STATS: emit per-block column sum/sumsq partials of the output.
// Inner loop: scalar sX reads (broadcast across the 16 col-lanes, 4 distinct
// banks across tr groups -> conflict-free; the float4-read variant had 2-way
// b128 conflicts and cost ~19us/GEMM).
// ---------------------------------------------------------------------------
template <int IN_MODE, bool ADD_BIAS, bool ROW_SCALE, bool STATS>
__global__ __launch_bounds__(256) void k_gemm(const float* __restrict__ X,
                                              const float* __restrict__ W,
                                              const float* __restrict__ bias,
                                              const float* __restrict__ dinv,
                                              const float* __restrict__ scsh,
                                              float* __restrict__ Y,
                                              float* __restrict__ partial, int n) {
    __shared__ float sW[64][64];   // [k][c]
    __shared__ float sX[64][66];
    const int tid  = threadIdx.x;
    const int row0 = blockIdx.x * 64;

    {   // load W (4096 floats) via float4
        const float4* Wv  = reinterpret_cast<const float4*>(W);
        float4*       sWv = reinterpret_cast<float4*>(&sW[0][0]);
        #pragma unroll
        for (int i = tid; i < 1024; i += 256) sWv[i] = Wv[i];
    }
    // load X tile (64x64) via float4 with fused BN/ReLU transform
    #pragma unroll
    for (int f = tid; f < 1024; f += 256) {
        int r = f >> 4, c4 = (f & 15) << 2;
        float4 v = make_float4(0.f, 0.f, 0.f, 0.f);
        if (row0 + r < n)
            v = *reinterpret_cast<const float4*>(&X[(size_t)(row0 + r) * HID + c4]);
        if (IN_MODE >= 1) {
            float4 sc = *reinterpret_cast<const float4*>(&scsh[c4]);
            float4 sh = *reinterpret_cast<const float4*>(&scsh[64 + c4]);
            v.x = v.x * sc.x + sh.x; v.y = v.y * sc.y + sh.y;
            v.z = v.z * sc.z + sh.z; v.w = v.w * sc.w + sh.w;
            if (IN_MODE == 2) {
                v.x = fmaxf(v.x, 0.f); v.y = fmaxf(v.y, 0.f);
                v.z = fmaxf(v.z, 0.f); v.w = fmaxf(v.w, 0.f);
            }
        }
        sX[r][c4 + 0] = v.x; sX[r][c4 + 1] = v.y;
        sX[r][c4 + 2] = v.z; sX[r][c4 + 3] = v.w;
    }
    __syncthreads();

    const int tr = tid >> 4;   // output rows tr*4..tr*4+3
    const int tc = tid & 15;   // output cols tc*4..tc*4+3
    float4 acc[4];
    #pragma unroll
    for (int i = 0; i < 4; ++i) acc[i] = make_float4(0.f, 0.f, 0.f, 0.f);

    #pragma unroll 16
    for (int k = 0; k < 64; ++k) {
        const float4 bv = *reinterpret_cast<const float4*>(&sW[k][tc << 2]);
        float a[4];
        #pragma unroll
        for (int i = 0; i < 4; ++i) a[i] = sX[(tr << 2) + i][k];
        #pragma unroll
        for (int i = 0; i < 4; ++i) {
            acc[i].x += a[i] * bv.x;
            acc[i].y += a[i] * bv.y;
            acc[i].z += a[i] * bv.z;
            acc[i].w += a[i] * bv.w;
        }
    }

    float4 bb = make_float4(0.f, 0.f, 0.f, 0.f);
    if (ADD_BIAS) bb = *reinterpret_cast<const float4*>(&bias[tc << 2]);

    float4 o[4];
    bool valid[4];
    #pragma unroll
    for (int i = 0; i < 4; ++i) {
        int r = row0 + (tr << 2) + i;
        valid[i] = (r < n);
        float s = ROW_SCALE ? (valid[i] ? dinv[r] : 1.f) : 1.f;
        o[i].x = acc[i].x * s + bb.x;
        o[i].y = acc[i].y * s + bb.y;
        o[i].z = acc[i].z * s + bb.z;
        o[i].w = acc[i].w * s + bb.w;
        if (valid[i])
            *reinterpret_cast<float4*>(&Y[(size_t)r * HID + (tc << 2)]) = o[i];
    }

    if (STATS) {
        float sx = 0.f, sy = 0.f, sz = 0.f, sw = 0.f;
        float qx = 0.f, qy = 0.f, qz = 0.f, qw = 0.f;
        #pragma unroll
        for (int i = 0; i < 4; ++i) {
            if (valid[i]) {
                sx += o[i].x; qx += o[i].x * o[i].x;
                sy += o[i].y; qy += o[i].y * o[i].y;
                sz += o[i].z; qz += o[i].z * o[i].z;
                sw += o[i].w; qw += o[i].w * o[i].w;
            }
        }
        __syncthreads();                       // done reading sX; safe to reuse
        float* st = &sX[0][0];                 // [0..1023]=sum, [1024..2047]=sq
        int cbase = (tc << 2);
        st[tr * 64 + cbase + 0] = sx; st[1024 + tr * 64 + cbase + 0] = qx;
        st[tr * 64 + cbase + 1] = sy; st[1024 + tr * 64 + cbase + 1] = qy;
        st[tr * 64 + cbase + 2] = sz; st[1024 + tr * 64 + cbase + 2] = qz;
        st[tr * 64 + cbase + 3] = sw; st[1024 + tr * 64 + cbase + 3] = qw;
        __syncthreads();
        if (tid < 64) {
            float S = 0.f, Q = 0.f;
            #pragma unroll
            for (int t = 0; t < 16; ++t) {
                S += st[t * 64 + tid];
                Q += st[1024 + t * 64 + tid];
            }
            partial[blockIdx.x * 128 + tid]      = S;
            partial[blockIdx.x * 128 + 64 + tid] = Q;
        }
    }
}

// Reduce per-block partials -> scale/shift. One block per column.
__global__ __launch_bounds__(256) void k_statsfin(const float* __restrict__ partial,
                                                  const float* __restrict__ g,
                                                  const float* __restrict__ beta,
                                                  float* __restrict__ scsh, int n) {
    int c = blockIdx.x, t = threadIdx.x;
    float S = 0.f, Q = 0.f;
    for (int b = t; b < GEMM_BLK; b += 256) {
        S += partial[b * 128 + c];
        Q += partial[b * 128 + 64 + c];
    }
    __shared__ float ss[256], sq[256];
    ss[t] = S; sq[t] = Q;
    __syncthreads();
    for (int off = 128; off > 0; off >>= 1) {
        if (t < off) { ss[t] += ss[t + off]; sq[t] += sq[t + off]; }
        __syncthreads();
    }
    if (t == 0) {
        float nf = (float)n;
        float m  = ss[0] / nf;
        float v  = sq[0] / nf - m * m;
        float sc = rsqrtf(v + BN_EPS) * g[c];
        scsh[c]      = sc;
        scsh[64 + c] = beta[c] - m * sc;
    }
}

// ---------------------------------------------------------------------------
// CSR build
// ---------------------------------------------------------------------------
__global__ __launch_bounds__(256) void k_deg(const int* __restrict__ dst,
                                             int* __restrict__ indeg) {
    int e = blockIdx.x * 256 + threadIdx.x;
    if (e < N_EDGES) atomicAdd(&indeg[dst[e]], 1);
}

__global__ __launch_bounds__(256) void k_scanpart(const int* __restrict__ indeg,
                                                  int* __restrict__ bsum) {
    __shared__ int s[256];
    int i = blockIdx.x * 256 + threadIdx.x;
    s[threadIdx.x] = (i < N_NODES) ? indeg[i] : 0;
    __syncthreads();
    for (int off = 128; off > 0; off >>= 1) {
        if (threadIdx.x < off) s[threadIdx.x] += s[threadIdx.x + off];
        __syncthreads();
    }
    if (threadIdx.x == 0) bsum[blockIdx.x] = s[0];
}

__global__ __launch_bounds__(512) void k_scanmid(int* __restrict__ bsum, int nblk) {
    __shared__ int s[512];
    int t = threadIdx.x;
    int v = (t < nblk) ? bsum[t] : 0;
    s[t] = v;
    __syncthreads();
    for (int off = 1; off < 512; off <<= 1) {
        int x = (t >= off) ? s[t - off] : 0;
        __syncthreads();
        s[t] += x;
        __syncthreads();
    }
    if (t < nblk) bsum[t] = s[t] - v;   // exclusive
}

__global__ __launch_bounds__(256) void k_scanfinal(const int* __restrict__ indeg,
                                                   const int* __restrict__ bsum,
                                                   int* __restrict__ rowptr) {
    __shared__ int s[256];
    int t = threadIdx.x;
    int i = blockIdx.x * 256 + t;
    int v = (i < N_NODES) ? indeg[i] : 0;
    s[t] = v;
    __syncthreads();
    for (int off = 1; off < 256; off <<= 1) {
        int x = (t >= off) ? s[t - off] : 0;
        __syncthreads();
        s[t] += x;
        __syncthreads();
    }
    if (i < N_NODES) rowptr[i] = bsum[blockIdx.x] + s[t] - v;
    if (i == 0) rowptr[N_NODES] = N_EDGES;
}

__global__ __launch_bounds__(256) void k_dinv(const int* __restrict__ indeg,
                                              float* __restrict__ dinv) {
    int i = blockIdx.x * 256 + threadIdx.x;
    if (i < N_NODES) dinv[i] = rsqrtf((float)indeg[i] + 1.f);
}

__global__ __launch_bounds__(256) void k_fill(const int* __restrict__ src,
                                              const int* __restrict__ dst,
                                              const int* __restrict__ rowptr,
                                              int* __restrict__ indeg,
                                              int* __restrict__ colidx) {
    int e = blockIdx.x * 256 + threadIdx.x;
    if (e >= N_EDGES) return;
    int d = dst[e];
    int pos = rowptr[d] + (atomicSub(&indeg[d], 1) - 1);
    colidx[pos] = src[e];
}

// ---------------------------------------------------------------------------
// Fused gather + conv finalize: one wave per dst node, 4 edge-slots x 16
// col-lanes x float4. 4 edge rows in flight per wave (latency hiding), then
// cross-slot shuffle reduce; lanes 0-15 run the epilogue.
// Out[d] = (sum_{s in N(d)} HW[s] + HW[d]) * dinv[d] + bias + T(Hin[d]), opt ReLU
// ---------------------------------------------------------------------------
template <int IN_MODE, bool RELU>
__global__ __launch_bounds__(256) void k_gather(const int* __restrict__ rowptr,
                                                const int* __restrict__ colidx,
                                                const float* __restrict__ HW,
                                                const float* __restrict__ Hin,
                                                const float* __restrict__ dinv,
                                                const float* __restrict__ bias,
                                                const float* __restrict__ scsh,
                                                float* __restrict__ Out) {
    int d = blockIdx.x * 4 + (threadIdx.x >> 6);
    if (d >= N_NODES) return;
    const int lane = threadIdx.x & 63;
    const int slot = lane >> 4;          // 0..3 edge slot
    const int c4   = (lane & 15) << 2;   // column base
    const int j0 = rowptr[d], j1 = rowptr[d + 1];

    float4 acc = make_float4(0.f, 0.f, 0.f, 0.f);
    if (slot == 3) {  // self-loop term (slot 3: keeps slot 0 free for epilogue)
        float4 v = *reinterpret_cast<const float4*>(&HW[(size_t)d * HID + c4]);
        acc.x = v.x; acc.y = v.y; acc.z = v.z; acc.w = v.w;
    }
    for (int j = j0 + slot; j < j1; j += 4) {
        int s = colidx[j];
        float4 v = *reinterpret_cast<const float4*>(&HW[(size_t)s * HID + c4]);
        acc.x += v.x; acc.y += v.y; acc.z += v.z; acc.w += v.w;
    }
    // reduce across the 4 slots (lane bits 4,5)
    acc.x += __shfl_xor(acc.x, 16); acc.y += __shfl_xor(acc.y, 16);
    acc.z += __shfl_xor(acc.z, 16); acc.w += __shfl_xor(acc.w, 16);
    acc.x += __shfl_xor(acc.x, 32); acc.y += __shfl_xor(acc.y, 32);
    acc.z += __shfl_xor(acc.z, 32); acc.w += __shfl_xor(acc.w, 32);

    if (slot == 0) {
        float4 hin = *reinterpret_cast<const float4*>(&Hin[(size_t)d * HID + c4]);
        if (IN_MODE == 1) {
            float4 sc = *reinterpret_cast<const float4*>(&scsh[c4]);
            float4 sh = *reinterpret_cast<const float4*>(&scsh[64 + c4]);
            hin.x = hin.x * sc.x + sh.x; hin.y = hin.y * sc.y + sh.y;
            hin.z = hin.z * sc.z + sh.z; hin.w = hin.w * sc.w + sh.w;
        }
        float di = dinv[d];
        float4 bb = *reinterpret_cast<const float4*>(&bias[c4]);
        float4 o;
        o.x = acc.x * di + bb.x + hin.x;
        o.y = acc.y * di + bb.y + hin.y;
        o.z = acc.z * di + bb.z + hin.z;
        o.w = acc.w * di + bb.w + hin.w;
        if (RELU) {
            o.x = fmaxf(o.x, 0.f); o.y = fmaxf(o.y, 0.f);
            o.z = fmaxf(o.z, 0.f); o.w = fmaxf(o.w, 0.f);
        }
        *reinterpret_cast<float4*>(&Out[(size_t)d * HID + c4]) = o;
    }
}

// ---------------------------------------------------------------------------
// Two-stage segment-mean pool over sorted batch + fused final BN
// ---------------------------------------------------------------------------
__device__ __forceinline__ int lowerb(const int* __restrict__ b, int n, int v) {
    int lo = 0, hi = n;
    while (lo < hi) { int m = (lo + hi) >> 1; if (b[m] < v) lo = m + 1; else hi = m; }
    return lo;
}

__global__ __launch_bounds__(256) void k_pool1(const float* __restrict__ Y,
                                               const int* __restrict__ batch,
                                               float* __restrict__ partial2) {
    int g  = blockIdx.x >> 4;
    int sb = blockIdx.x & 15;
    int tid = threadIdx.x, col = tid & 63, rg = tid >> 6;
    int lo = lowerb(batch, N_NODES, g);
    int hi = lowerb(batch, N_NODES, g + 1);
    int cnt = hi - lo;
    int st = lo + (int)(((long long)cnt * sb) >> 4);
    int en = lo + (int)(((long long)cnt * (sb + 1)) >> 4);
    float s = 0.f;
    for (int r = st + rg; r < en; r += 4) s += Y[(size_t)r * HID + col];
    __shared__ float ls[4][64];
    ls[rg][col] = s;
    __syncthreads();
    if (tid < 64)
        partial2[(size_t)blockIdx.x * 64 + tid] =
            ls[0][tid] + ls[1][tid] + ls[2][tid] + ls[3][tid];
}

__global__ __launch_bounds__(64) void k_pool2(const float* __restrict__ partial2,
                                              const int* __restrict__ batch,
                                              const float* __restrict__ scsh,
                                              float* __restrict__ pooled) {
    int g = blockIdx.x, c = threadIdx.x;
    float S = 0.f;
    #pragma unroll
    for (int sb = 0; sb < POOL_SUB; ++sb)
        S += partial2[(size_t)(g * POOL_SUB + sb) * 64 + c];
    int lo = lowerb(batch, N_NODES, g);
    int hi = lowerb(batch, N_NODES, g + 1);
    int cnt = hi - lo;
    float out = 0.f;
    if (cnt > 0) {
        float mean = S / (float)cnt;
        out = mean * scsh[c] + scsh[64 + c];
    }
    pooled[g * 64 + c] = out;
}

// ---------------------------------------------------------------------------
// Final head
// ---------------------------------------------------------------------------
__global__ __launch_bounds__(256) void k_final(const float* __restrict__ pooled,
                                               const float* __restrict__ W0,
                                               const float* __restrict__ b0,
                                               const float* __restrict__ W1,
                                               const float* __restrict__ b1,
                                               const float* __restrict__ W2,
                                               const float* __restrict__ b2,
                                               float* __restrict__ out) {
    __shared__ float P[64][65];
    __shared__ float Z[64][65];
    int tid = threadIdx.x;
    for (int i = tid; i < NGRAPH * HID; i += 256) P[i >> 6][i & 63] = pooled[i];
    __syncthreads();
    for (int t = 0; t < 16; ++t) {
        int o = tid + 256 * t; int r = o >> 6, c = o & 63;
        float acc = b0[c];
        #pragma unroll 8
        for (int k = 0; k < 64; ++k) acc += P[r][k] * W0[k * 64 + c];
        Z[r][c] = fmaxf(acc, 0.f);
    }
    __syncthreads();
    for (int t = 0; t < 16; ++t) {
        int o = tid + 256 * t; int r = o >> 6, c = o & 63;
        float acc = b1[c];
        #pragma unroll 8
        for (int k = 0; k < 64; ++k) acc += Z[r][k] * W1[k * 64 + c];
        P[r][c] = fmaxf(acc, 0.f);
    }
    __syncthreads();
    if (tid < NGRAPH * OUTC) {
        int r = tid >> 1, c = tid & 1;
        float acc = b2[c];
        #pragma unroll 8
        for (int k = 0; k < 64; ++k) acc += P[r][k] * W2[k * OUTC + c];
        out[tid] = acc;
    }
}

// ---------------------------------------------------------------------------
extern "C" void kernel_launch(void* const* d_in, const int* in_sizes, int n_in,
                              void* d_out, int out_size, void* d_ws, size_t ws_size,
                              hipStream_t stream) {
    const float* x        = (const float*)d_in[0];
    const int*   ei       = (const int*)d_in[1];
    const int*   batch    = (const int*)d_in[2];
    const float* pre_W    = (const float*)d_in[3];
    const float* pre_b    = (const float*)d_in[4];
    const float* pre_g    = (const float*)d_in[5];
    const float* pre_beta = (const float*)d_in[6];
    const float* conv_W   = (const float*)d_in[7];
    const float* conv_b   = (const float*)d_in[8];
    const float* post_W   = (const float*)d_in[9];
    const float* post_b   = (const float*)d_in[10];
    const float* post_g   = (const float*)d_in[11];
    const float* post_beta= (const float*)d_in[12];
    const float* fW0 = (const float*)d_in[13];
    const float* fb0 = (const float*)d_in[14];
    const float* fW1 = (const float*)d_in[15];
    const float* fb1 = (const float*)d_in[16];
    const float* fW2 = (const float*)d_in[17];
    const float* fb2 = (const float*)d_in[18];
    float* out = (float*)d_out;

    const size_t NH = (size_t)N_NODES * HID;
    float* ws       = (float*)d_ws;
    float* A        = ws;
    float* B        = A + NH;
    float* C        = B + NH;
    float* dinv     = C + NH;                         // N
    float* partial  = dinv + N_NODES;                 // GEMM_BLK*128
    float* scsh     = partial + (size_t)GEMM_BLK*128; // 6 slots of 128
    float* pooled   = scsh + 6 * 128;                 // 64*64
    float* partial2 = pooled + NGRAPH * HID;          // 1024*64
    int*   indeg    = (int*)(partial2 + NGRAPH * POOL_SUB * 64);
    int*   rowptr   = indeg + N_NODES;                // N+1
    int*   colidx   = rowptr + N_NODES + 1;           // E
    int*   bsum     = colidx + N_EDGES;               // NSCAN_BLK

    const int* srcp = ei;
    const int* dstp = ei + N_EDGES;

    const int gEdge  = (N_EDGES + 255) / 256;
    const int gNode  = (N_NODES + 255) / 256;
    const int gNode4 = (N_NODES + 3) / 4;

    // ---- CSR build ----
    hipMemsetAsync(indeg, 0, N_NODES * sizeof(int), stream);
    k_deg<<<gEdge, 256, 0, stream>>>(dstp, indeg);
    k_scanpart<<<NSCAN_BLK, 256, 0, stream>>>(indeg, bsum);
    k_scanmid<<<1, 512, 0, stream>>>(bsum, NSCAN_BLK);
    k_scanfinal<<<NSCAN_BLK, 256, 0, stream>>>(indeg, bsum, rowptr);
    k_dinv<<<gNode, 256, 0, stream>>>(indeg, dinv);
    k_fill<<<gEdge, 256, 0, stream>>>(srcp, dstp, rowptr, indeg, colidx);

    // ---- pre-processing: GEMM(+fused prev BN/ReLU, +stats) ----
    k_gemm<0, true, false, true><<<GEMM_BLK, 256, 0, stream>>>(x, pre_W, pre_b, nullptr, nullptr, A, partial, N_NODES);
    k_statsfin<<<64, 256, 0, stream>>>(partial, pre_g, pre_beta, scsh + 0 * 128, N_NODES);

    k_gemm<2, true, false, true><<<GEMM_BLK, 256, 0, stream>>>(A, pre_W + 4096, pre_b + 64, nullptr, scsh + 0 * 128, B, partial, N_NODES);
    k_statsfin<<<64, 256, 0, stream>>>(partial, pre_g + 64, pre_beta + 64, scsh + 1 * 128, N_NODES);

    k_gemm<2, true, false, true><<<GEMM_BLK, 256, 0, stream>>>(B, pre_W + 2 * 4096, pre_b + 128, nullptr, scsh + 1 * 128, A, partial, N_NODES);
    k_statsfin<<<64, 256, 0, stream>>>(partial, pre_g + 128, pre_beta + 128, scsh + 2 * 128, N_NODES);

    // ---- GCNConv stack ----
    for (int i = 0; i < 6; ++i) {
        const float* in = (i & 1) ? C : A;
        float*     outb = (i & 1) ? A : C;
        const float* Wl = conv_W + i * 4096;
        const float* bl = conv_b + i * 64;
        if (i == 0)
            k_gemm<1, false, true, false><<<GEMM_BLK, 256, 0, stream>>>(in, Wl, nullptr, dinv, scsh + 2 * 128, B, nullptr, N_NODES);
        else
            k_gemm<0, false, true, false><<<GEMM_BLK, 256, 0, stream>>>(in, Wl, nullptr, dinv, nullptr, B, nullptr, N_NODES);

        if (i == 0)
            k_gather<1, true ><<<gNode4, 256, 0, stream>>>(rowptr, colidx, B, in, dinv, bl, scsh + 2 * 128, outb);
        else if (i != 5)
            k_gather<0, true ><<<gNode4, 256, 0, stream>>>(rowptr, colidx, B, in, dinv, bl, nullptr, outb);
        else
            k_gather<0, false><<<gNode4, 256, 0, stream>>>(rowptr, colidx, B, in, dinv, bl, nullptr, outb);
    }
    // conv output in A

    // ---- post-processing ----
    k_gemm<0, true, false, true><<<GEMM_BLK, 256, 0, stream>>>(A, post_W, post_b, nullptr, nullptr, B, partial, N_NODES);
    k_statsfin<<<64, 256, 0, stream>>>(partial, post_g, post_beta, scsh + 3 * 128, N_NODES);

    k_gemm<2, true, false, true><<<GEMM_BLK, 256, 0, stream>>>(B, post_W + 4096, post_b + 64, nullptr, scsh + 3 * 128, C, partial, N_NODES);
    k_statsfin<<<64, 256, 0, stream>>>(partial, post_g + 64, post_beta + 64, scsh + 4 * 128, N_NODES);

    k_gemm<2, true, false, true><<<GEMM_BLK, 256, 0, stream>>>(C, post_W + 2 * 4096, post_b + 128, nullptr, scsh + 4 * 128, B, partial, N_NODES);
    k_statsfin<<<64, 256, 0, stream>>>(partial, post_g + 128, post_beta + 128, scsh + 5 * 128, N_NODES);

    // ---- pool (two-stage segment mean, fused final BN) + head ----
    k_pool1<<<NGRAPH * POOL_SUB, 256, 0, stream>>>(B, batch, partial2);
    k_pool2<<<NGRAPH, 64, 0, stream>>>(partial2, batch, scsh + 5 * 128, pooled);
    k_final<<<1, 256, 0, stream>>>(pooled, fW0, fb0, fW1, fb1, fW2, fb2, out);
}

// Round 5
// 669.423 us; speedup vs baseline: 1.8898x; 1.0511x over previous
//
#include <hip/hip_runtime.h>

#define N_NODES 100000
#define N_EDGES 800000
#define HID 64
#define NGRAPH 64
#define OUTC 2
#define BN_EPS 1e-5f
#define NSCAN_BLK ((N_NODES + 255) / 256)   // 391
#define GEMM_BLK ((N_NODES + 63) / 64)      // 1563
#define POOL_SUB 16

__device__ __forceinline__ unsigned short f2bf(float f) {
    unsigned int u = __float_as_uint(f);
    u = (u + 0x7FFFu + ((u >> 16) & 1u)) >> 16;   // round-to-nearest-even
    return (unsigned short)u;
}

// ---------------------------------------------------------------------------
// GEMM: Y[n,64] = T(X)[n,64] @ W[64,64] (+bias) (opt row-scale by dinv)
// T(X) = optional per-column BN (scale/shift) + optional ReLU, fused on load.
// IN_MODE: 0 = identity, 1 = BN, 2 = BN + ReLU
// STATS: emit per-block column sum/sumsq partials of the output (fp32 out only).
// OUT_BF16: write Y as bf16 (conv HW buffer; halves gather fetch traffic).
// Inner loop: scalar sX reads (broadcast across the 16 col-lanes) -- the
// float4-read variant had 2-way b128 conflicts and cost ~19us/GEMM (round 3).
// ---------------------------------------------------------------------------
template <int IN_MODE, bool ADD_BIAS, bool ROW_SCALE, bool STATS, bool OUT_BF16>
__global__ __launch_bounds__(256) void k_gemm(const float* __restrict__ X,
                                              const float* __restrict__ W,
                                              const float* __restrict__ bias,
                                              const float* __restrict__ dinv,
                                              const float* __restrict__ scsh,
                                              void* __restrict__ Yv,
                                              float* __restrict__ partial, int n) {
    __shared__ float sW[64][64];   // [k][c]
    __shared__ float sX[64][66];
    const int tid  = threadIdx.x;
    const int row0 = blockIdx.x * 64;

    {   // load W (4096 floats) via float4
        const float4* Wv  = reinterpret_cast<const float4*>(W);
        float4*       sWv = reinterpret_cast<float4*>(&sW[0][0]);
        #pragma unroll
        for (int i = tid; i < 1024; i += 256) sWv[i] = Wv[i];
    }
    // load X tile (64x64) via float4 with fused BN/ReLU transform
    #pragma unroll
    for (int f = tid; f < 1024; f += 256) {
        int r = f >> 4, c4 = (f & 15) << 2;
        float4 v = make_float4(0.f, 0.f, 0.f, 0.f);
        if (row0 + r < n)
            v = *reinterpret_cast<const float4*>(&X[(size_t)(row0 + r) * HID + c4]);
        if (IN_MODE >= 1) {
            float4 sc = *reinterpret_cast<const float4*>(&scsh[c4]);
            float4 sh = *reinterpret_cast<const float4*>(&scsh[64 + c4]);
            v.x = v.x * sc.x + sh.x; v.y = v.y * sc.y + sh.y;
            v.z = v.z * sc.z + sh.z; v.w = v.w * sc.w + sh.w;
            if (IN_MODE == 2) {
                v.x = fmaxf(v.x, 0.f); v.y = fmaxf(v.y, 0.f);
                v.z = fmaxf(v.z, 0.f); v.w = fmaxf(v.w, 0.f);
            }
        }
        sX[r][c4 + 0] = v.x; sX[r][c4 + 1] = v.y;
        sX[r][c4 + 2] = v.z; sX[r][c4 + 3] = v.w;
    }
    __syncthreads();

    const int tr = tid >> 4;   // output rows tr*4..tr*4+3
    const int tc = tid & 15;   // output cols tc*4..tc*4+3
    float4 acc[4];
    #pragma unroll
    for (int i = 0; i < 4; ++i) acc[i] = make_float4(0.f, 0.f, 0.f, 0.f);

    #pragma unroll 16
    for (int k = 0; k < 64; ++k) {
        const float4 bv = *reinterpret_cast<const float4*>(&sW[k][tc << 2]);
        float a[4];
        #pragma unroll
        for (int i = 0; i < 4; ++i) a[i] = sX[(tr << 2) + i][k];
        #pragma unroll
        for (int i = 0; i < 4; ++i) {
            acc[i].x += a[i] * bv.x;
            acc[i].y += a[i] * bv.y;
            acc[i].z += a[i] * bv.z;
            acc[i].w += a[i] * bv.w;
        }
    }

    float4 bb = make_float4(0.f, 0.f, 0.f, 0.f);
    if (ADD_BIAS) bb = *reinterpret_cast<const float4*>(&bias[tc << 2]);

    float4 o[4];
    bool valid[4];
    #pragma unroll
    for (int i = 0; i < 4; ++i) {
        int r = row0 + (tr << 2) + i;
        valid[i] = (r < n);
        float s = ROW_SCALE ? (valid[i] ? dinv[r] : 1.f) : 1.f;
        o[i].x = acc[i].x * s + bb.x;
        o[i].y = acc[i].y * s + bb.y;
        o[i].z = acc[i].z * s + bb.z;
        o[i].w = acc[i].w * s + bb.w;
        if (valid[i]) {
            if (OUT_BF16) {
                ushort4 p;
                p.x = f2bf(o[i].x); p.y = f2bf(o[i].y);
                p.z = f2bf(o[i].z); p.w = f2bf(o[i].w);
                *reinterpret_cast<ushort4*>(
                    &((unsigned short*)Yv)[(size_t)r * HID + (tc << 2)]) = p;
            } else {
                *reinterpret_cast<float4*>(
                    &((float*)Yv)[(size_t)r * HID + (tc << 2)]) = o[i];
            }
        }
    }

    if (STATS) {
        float sx = 0.f, sy = 0.f, sz = 0.f, sw = 0.f;
        float qx = 0.f, qy = 0.f, qz = 0.f, qw = 0.f;
        #pragma unroll
        for (int i = 0; i < 4; ++i) {
            if (valid[i]) {
                sx += o[i].x; qx += o[i].x * o[i].x;
                sy += o[i].y; qy += o[i].y * o[i].y;
                sz += o[i].z; qz += o[i].z * o[i].z;
                sw += o[i].w; qw += o[i].w * o[i].w;
            }
        }
        __syncthreads();                       // done reading sX; safe to reuse
        float* st = &sX[0][0];                 // [0..1023]=sum, [1024..2047]=sq
        int cbase = (tc << 2);
        st[tr * 64 + cbase + 0] = sx; st[1024 + tr * 64 + cbase + 0] = qx;
        st[tr * 64 + cbase + 1] = sy; st[1024 + tr * 64 + cbase + 1] = qy;
        st[tr * 64 + cbase + 2] = sz; st[1024 + tr * 64 + cbase + 2] = qz;
        st[tr * 64 + cbase + 3] = sw; st[1024 + tr * 64 + cbase + 3] = qw;
        __syncthreads();
        if (tid < 64) {
            float S = 0.f, Q = 0.f;
            #pragma unroll
            for (int t = 0; t < 16; ++t) {
                S += st[t * 64 + tid];
                Q += st[1024 + t * 64 + tid];
            }
            partial[blockIdx.x * 128 + tid]      = S;
            partial[blockIdx.x * 128 + 64 + tid] = Q;
        }
    }
}

// Reduce per-block partials -> scale/shift. One block per column.
__global__ __launch_bounds__(256) void k_statsfin(const float* __restrict__ partial,
                                                  const float* __restrict__ g,
                                                  const float* __restrict__ beta,
                                                  float* __restrict__ scsh, int n) {
    int c = blockIdx.x, t = threadIdx.x;
    float S = 0.f, Q = 0.f;
    for (int b = t; b < GEMM_BLK; b += 256) {
        S += partial[b * 128 + c];
        Q += partial[b * 128 + 64 + c];
    }
    __shared__ float ss[256], sq[256];
    ss[t] = S; sq[t] = Q;
    __syncthreads();
    for (int off = 128; off > 0; off >>= 1) {
        if (t < off) { ss[t] += ss[t + off]; sq[t] += sq[t + off]; }
        __syncthreads();
    }
    if (t == 0) {
        float nf = (float)n;
        float m  = ss[0] / nf;
        float v  = sq[0] / nf - m * m;
        float sc = rsqrtf(v + BN_EPS) * g[c];
        scsh[c]      = sc;
        scsh[64 + c] = beta[c] - m * sc;
    }
}

// ---------------------------------------------------------------------------
// CSR build
// ---------------------------------------------------------------------------
__global__ __launch_bounds__(256) void k_deg(const int* __restrict__ dst,
                                             int* __restrict__ indeg) {
    int e = blockIdx.x * 256 + threadIdx.x;
    if (e < N_EDGES) atomicAdd(&indeg[dst[e]], 1);
}

__global__ __launch_bounds__(256) void k_scanpart(const int* __restrict__ indeg,
                                                  int* __restrict__ bsum) {
    __shared__ int s[256];
    int i = blockIdx.x * 256 + threadIdx.x;
    s[threadIdx.x] = (i < N_NODES) ? indeg[i] : 0;
    __syncthreads();
    for (int off = 128; off > 0; off >>= 1) {
        if (threadIdx.x < off) s[threadIdx.x] += s[threadIdx.x + off];
        __syncthreads();
    }
    if (threadIdx.x == 0) bsum[blockIdx.x] = s[0];
}

__global__ __launch_bounds__(512) void k_scanmid(int* __restrict__ bsum, int nblk) {
    __shared__ int s[512];
    int t = threadIdx.x;
    int v = (t < nblk) ? bsum[t] : 0;
    s[t] = v;
    __syncthreads();
    for (int off = 1; off < 512; off <<= 1) {
        int x = (t >= off) ? s[t - off] : 0;
        __syncthreads();
        s[t] += x;
        __syncthreads();
    }
    if (t < nblk) bsum[t] = s[t] - v;   // exclusive
}

__global__ __launch_bounds__(256) void k_scanfinal(const int* __restrict__ indeg,
                                                   const int* __restrict__ bsum,
                                                   int* __restrict__ rowptr) {
    __shared__ int s[256];
    int t = threadIdx.x;
    int i = blockIdx.x * 256 + t;
    int v = (i < N_NODES) ? indeg[i] : 0;
    s[t] = v;
    __syncthreads();
    for (int off = 1; off < 256; off <<= 1) {
        int x = (t >= off) ? s[t - off] : 0;
        __syncthreads();
        s[t] += x;
        __syncthreads();
    }
    if (i < N_NODES) rowptr[i] = bsum[blockIdx.x] + s[t] - v;
    if (i == 0) rowptr[N_NODES] = N_EDGES;
}

__global__ __launch_bounds__(256) void k_dinv(const int* __restrict__ indeg,
                                              float* __restrict__ dinv) {
    int i = blockIdx.x * 256 + threadIdx.x;
    if (i < N_NODES) dinv[i] = rsqrtf((float)indeg[i] + 1.f);
}

__global__ __launch_bounds__(256) void k_fill(const int* __restrict__ src,
                                              const int* __restrict__ dst,
                                              const int* __restrict__ rowptr,
                                              int* __restrict__ indeg,
                                              int* __restrict__ colidx) {
    int e = blockIdx.x * 256 + threadIdx.x;
    if (e >= N_EDGES) return;
    int d = dst[e];
    int pos = rowptr[d] + (atomicSub(&indeg[d], 1) - 1);
    colidx[pos] = src[e];
}

// ---------------------------------------------------------------------------
// Fused gather + conv finalize: one wave per dst node, 8 edge-slots x 8
// col-lanes x bf16x8 (16B/lane). HW rows are bf16 (half the fetch bytes);
// accumulation fp32. Cross-slot reduce via 3 shfl_xor rounds; slot 0 runs
// the fp32 epilogue (dinv, bias, residual(+BN), ReLU) and the float4 stores.
// ---------------------------------------------------------------------------
template <int IN_MODE, bool RELU>
__global__ __launch_bounds__(256) void k_gather(const int* __restrict__ rowptr,
                                                const int* __restrict__ colidx,
                                                const unsigned short* __restrict__ HWb,
                                                const float* __restrict__ Hin,
                                                const float* __restrict__ dinv,
                                                const float* __restrict__ bias,
                                                const float* __restrict__ scsh,
                                                float* __restrict__ Out) {
    int d = blockIdx.x * 4 + (threadIdx.x >> 6);
    if (d >= N_NODES) return;
    const int lane = threadIdx.x & 63;
    const int slot = lane >> 3;          // 0..7 edge slot
    const int c8   = (lane & 7) << 3;    // column base (8 cols per lane)
    const int j0 = rowptr[d], j1 = rowptr[d + 1];

    float acc[8];
    #pragma unroll
    for (int k = 0; k < 8; ++k) acc[k] = 0.f;

    if (slot == 7) {  // self-loop term
        uint4 v = *reinterpret_cast<const uint4*>(&HWb[(size_t)d * HID + c8]);
        acc[0] += __uint_as_float(v.x << 16);
        acc[1] += __uint_as_float(v.x & 0xFFFF0000u);
        acc[2] += __uint_as_float(v.y << 16);
        acc[3] += __uint_as_float(v.y & 0xFFFF0000u);
        acc[4] += __uint_as_float(v.z << 16);
        acc[5] += __uint_as_float(v.z & 0xFFFF0000u);
        acc[6] += __uint_as_float(v.w << 16);
        acc[7] += __uint_as_float(v.w & 0xFFFF0000u);
    }
    for (int j = j0 + slot; j < j1; j += 8) {
        int s = colidx[j];
        uint4 v = *reinterpret_cast<const uint4*>(&HWb[(size_t)s * HID + c8]);
        acc[0] += __uint_as_float(v.x << 16);
        acc[1] += __uint_as_float(v.x & 0xFFFF0000u);
        acc[2] += __uint_as_float(v.y << 16);
        acc[3] += __uint_as_float(v.y & 0xFFFF0000u);
        acc[4] += __uint_as_float(v.z << 16);
        acc[5] += __uint_as_float(v.z & 0xFFFF0000u);
        acc[6] += __uint_as_float(v.w << 16);
        acc[7] += __uint_as_float(v.w & 0xFFFF0000u);
    }
    // reduce across the 8 slots (lane bits 3,4,5)
    #pragma unroll
    for (int m = 8; m < 64; m <<= 1) {
        #pragma unroll
        for (int k = 0; k < 8; ++k) acc[k] += __shfl_xor(acc[k], m);
    }

    if (slot == 0) {
        float4 h0 = *reinterpret_cast<const float4*>(&Hin[(size_t)d * HID + c8]);
        float4 h1 = *reinterpret_cast<const float4*>(&Hin[(size_t)d * HID + c8 + 4]);
        if (IN_MODE == 1) {
            float4 sc0 = *reinterpret_cast<const float4*>(&scsh[c8]);
            float4 sc1 = *reinterpret_cast<const float4*>(&scsh[c8 + 4]);
            float4 sh0 = *reinterpret_cast<const float4*>(&scsh[64 + c8]);
            float4 sh1 = *reinterpret_cast<const float4*>(&scsh[64 + c8 + 4]);
            h0.x = h0.x * sc0.x + sh0.x; h0.y = h0.y * sc0.y + sh0.y;
            h0.z = h0.z * sc0.z + sh0.z; h0.w = h0.w * sc0.w + sh0.w;
            h1.x = h1.x * sc1.x + sh1.x; h1.y = h1.y * sc1.y + sh1.y;
            h1.z = h1.z * sc1.z + sh1.z; h1.w = h1.w * sc1.w + sh1.w;
        }
        float di = dinv[d];
        float4 b0 = *reinterpret_cast<const float4*>(&bias[c8]);
        float4 b1 = *reinterpret_cast<const float4*>(&bias[c8 + 4]);
        float4 o0, o1;
        o0.x = acc[0] * di + b0.x + h0.x;
        o0.y = acc[1] * di + b0.y + h0.y;
        o0.z = acc[2] * di + b0.z + h0.z;
        o0.w = acc[3] * di + b0.w + h0.w;
        o1.x = acc[4] * di + b1.x + h1.x;
        o1.y = acc[5] * di + b1.y + h1.y;
        o1.z = acc[6] * di + b1.z + h1.z;
        o1.w = acc[7] * di + b1.w + h1.w;
        if (RELU) {
            o0.x = fmaxf(o0.x, 0.f); o0.y = fmaxf(o0.y, 0.f);
            o0.z = fmaxf(o0.z, 0.f); o0.w = fmaxf(o0.w, 0.f);
            o1.x = fmaxf(o1.x, 0.f); o1.y = fmaxf(o1.y, 0.f);
            o1.z = fmaxf(o1.z, 0.f); o1.w = fmaxf(o1.w, 0.f);
        }
        *reinterpret_cast<float4*>(&Out[(size_t)d * HID + c8])     = o0;
        *reinterpret_cast<float4*>(&Out[(size_t)d * HID + c8 + 4]) = o1;
    }
}

// ---------------------------------------------------------------------------
// Two-stage segment-mean pool over sorted batch + fused final BN
// ---------------------------------------------------------------------------
__device__ __forceinline__ int lowerb(const int* __restrict__ b, int n, int v) {
    int lo = 0, hi = n;
    while (lo < hi) { int m = (lo + hi) >> 1; if (b[m] < v) lo = m + 1; else hi = m; }
    return lo;
}

__global__ __launch_bounds__(256) void k_pool1(const float* __restrict__ Y,
                                               const int* __restrict__ batch,
                                               float* __restrict__ partial2) {
    int g  = blockIdx.x >> 4;
    int sb = blockIdx.x & 15;
    int tid = threadIdx.x, col = tid & 63, rg = tid >> 6;
    int lo = lowerb(batch, N_NODES, g);
    int hi = lowerb(batch, N_NODES, g + 1);
    int cnt = hi - lo;
    int st = lo + (int)(((long long)cnt * sb) >> 4);
    int en = lo + (int)(((long long)cnt * (sb + 1)) >> 4);
    float s = 0.f;
    for (int r = st + rg; r < en; r += 4) s += Y[(size_t)r * HID + col];
    __shared__ float ls[4][64];
    ls[rg][col] = s;
    __syncthreads();
    if (tid < 64)
        partial2[(size_t)blockIdx.x * 64 + tid] =
            ls[0][tid] + ls[1][tid] + ls[2][tid] + ls[3][tid];
}

__global__ __launch_bounds__(64) void k_pool2(const float* __restrict__ partial2,
                                              const int* __restrict__ batch,
                                              const float* __restrict__ scsh,
                                              float* __restrict__ pooled) {
    int g = blockIdx.x, c = threadIdx.x;
    float S = 0.f;
    #pragma unroll
    for (int sb = 0; sb < POOL_SUB; ++sb)
        S += partial2[(size_t)(g * POOL_SUB + sb) * 64 + c];
    int lo = lowerb(batch, N_NODES, g);
    int hi = lowerb(batch, N_NODES, g + 1);
    int cnt = hi - lo;
    float out = 0.f;
    if (cnt > 0) {
        float mean = S / (float)cnt;
        out = mean * scsh[c] + scsh[64 + c];
    }
    pooled[g * 64 + c] = out;
}

// ---------------------------------------------------------------------------
// Final head
// ---------------------------------------------------------------------------
__global__ __launch_bounds__(256) void k_final(const float* __restrict__ pooled,
                                               const float* __restrict__ W0,
                                               const float* __restrict__ b0,
                                               const float* __restrict__ W1,
                                               const float* __restrict__ b1,
                                               const float* __restrict__ W2,
                                               const float* __restrict__ b2,
                                               float* __restrict__ out) {
    __shared__ float P[64][65];
    __shared__ float Z[64][65];
    int tid = threadIdx.x;
    for (int i = tid; i < NGRAPH * HID; i += 256) P[i >> 6][i & 63] = pooled[i];
    __syncthreads();
    for (int t = 0; t < 16; ++t) {
        int o = tid + 256 * t; int r = o >> 6, c = o & 63;
        float acc = b0[c];
        #pragma unroll 8
        for (int k = 0; k < 64; ++k) acc += P[r][k] * W0[k * 64 + c];
        Z[r][c] = fmaxf(acc, 0.f);
    }
    __syncthreads();
    for (int t = 0; t < 16; ++t) {
        int o = tid + 256 * t; int r = o >> 6, c = o & 63;
        float acc = b1[c];
        #pragma unroll 8
        for (int k = 0; k < 64; ++k) acc += Z[r][k] * W1[k * 64 + c];
        P[r][c] = fmaxf(acc, 0.f);
    }
    __syncthreads();
    if (tid < NGRAPH * OUTC) {
        int r = tid >> 1, c = tid & 1;
        float acc = b2[c];
        #pragma unroll 8
        for (int k = 0; k < 64; ++k) acc += P[r][k] * W2[k * OUTC + c];
        out[tid] = acc;
    }
}

// ---------------------------------------------------------------------------
extern "C" void kernel_launch(void* const* d_in, const int* in_sizes, int n_in,
                              void* d_out, int out_size, void* d_ws, size_t ws_size,
                              hipStream_t stream) {
    const float* x        = (const float*)d_in[0];
    const int*   ei       = (const int*)d_in[1];
    const int*   batch    = (const int*)d_in[2];
    const float* pre_W    = (const float*)d_in[3];
    const float* pre_b    = (const float*)d_in[4];
    const float* pre_g    = (const float*)d_in[5];
    const float* pre_beta = (const float*)d_in[6];
    const float* conv_W   = (const float*)d_in[7];
    const float* conv_b   = (const float*)d_in[8];
    const float* post_W   = (const float*)d_in[9];
    const float* post_b   = (const float*)d_in[10];
    const float* post_g   = (const float*)d_in[11];
    const float* post_beta= (const float*)d_in[12];
    const float* fW0 = (const float*)d_in[13];
    const float* fb0 = (const float*)d_in[14];
    const float* fW1 = (const float*)d_in[15];
    const float* fb1 = (const float*)d_in[16];
    const float* fW2 = (const float*)d_in[17];
    const float* fb2 = (const float*)d_in[18];
    float* out = (float*)d_out;

    const size_t NH = (size_t)N_NODES * HID;
    float* ws       = (float*)d_ws;
    float* A        = ws;
    float* B        = A + NH;          // bf16 HW buffer lives here (NH ushorts)
    float* C        = B + NH;
    float* dinv     = C + NH;                         // N
    float* partial  = dinv + N_NODES;                 // GEMM_BLK*128
    float* scsh     = partial + (size_t)GEMM_BLK*128; // 6 slots of 128
    float* pooled   = scsh + 6 * 128;                 // 64*64
    float* partial2 = pooled + NGRAPH * HID;          // 1024*64
    int*   indeg    = (int*)(partial2 + NGRAPH * POOL_SUB * 64);
    int*   rowptr   = indeg + N_NODES;                // N+1
    int*   colidx   = rowptr + N_NODES + 1;           // E
    int*   bsum     = colidx + N_EDGES;               // NSCAN_BLK
    unsigned short* HWb = (unsigned short*)B;

    const int* srcp = ei;
    const int* dstp = ei + N_EDGES;

    const int gEdge  = (N_EDGES + 255) / 256;
    const int gNode  = (N_NODES + 255) / 256;
    const int gNode4 = (N_NODES + 3) / 4;

    // ---- CSR build ----
    hipMemsetAsync(indeg, 0, N_NODES * sizeof(int), stream);
    k_deg<<<gEdge, 256, 0, stream>>>(dstp, indeg);
    k_scanpart<<<NSCAN_BLK, 256, 0, stream>>>(indeg, bsum);
    k_scanmid<<<1, 512, 0, stream>>>(bsum, NSCAN_BLK);
    k_scanfinal<<<NSCAN_BLK, 256, 0, stream>>>(indeg, bsum, rowptr);
    k_dinv<<<gNode, 256, 0, stream>>>(indeg, dinv);
    k_fill<<<gEdge, 256, 0, stream>>>(srcp, dstp, rowptr, indeg, colidx);

    // ---- pre-processing: GEMM(+fused prev BN/ReLU, +stats) ----
    k_gemm<0, true, false, true, false><<<GEMM_BLK, 256, 0, stream>>>(x, pre_W, pre_b, nullptr, nullptr, A, partial, N_NODES);
    k_statsfin<<<64, 256, 0, stream>>>(partial, pre_g, pre_beta, scsh + 0 * 128, N_NODES);

    k_gemm<2, true, false, true, false><<<GEMM_BLK, 256, 0, stream>>>(A, pre_W + 4096, pre_b + 64, nullptr, scsh + 0 * 128, (float*)(C), partial, N_NODES);
    k_statsfin<<<64, 256, 0, stream>>>(partial, pre_g + 64, pre_beta + 64, scsh + 1 * 128, N_NODES);

    k_gemm<2, true, false, true, false><<<GEMM_BLK, 256, 0, stream>>>(C, pre_W + 2 * 4096, pre_b + 128, nullptr, scsh + 1 * 128, A, partial, N_NODES);
    k_statsfin<<<64, 256, 0, stream>>>(partial, pre_g + 128, pre_beta + 128, scsh + 2 * 128, N_NODES);

    // ---- GCNConv stack (HW in bf16) ----
    for (int i = 0; i < 6; ++i) {
        const float* in = (i & 1) ? C : A;
        float*     outb = (i & 1) ? A : C;
        const float* Wl = conv_W + i * 4096;
        const float* bl = conv_b + i * 64;
        if (i == 0)
            k_gemm<1, false, true, false, true><<<GEMM_BLK, 256, 0, stream>>>(in, Wl, nullptr, dinv, scsh + 2 * 128, HWb, nullptr, N_NODES);
        else
            k_gemm<0, false, true, false, true><<<GEMM_BLK, 256, 0, stream>>>(in, Wl, nullptr, dinv, nullptr, HWb, nullptr, N_NODES);

        if (i == 0)
            k_gather<1, true ><<<gNode4, 256, 0, stream>>>(rowptr, colidx, HWb, in, dinv, bl, scsh + 2 * 128, outb);
        else if (i != 5)
            k_gather<0, true ><<<gNode4, 256, 0, stream>>>(rowptr, colidx, HWb, in, dinv, bl, nullptr, outb);
        else
            k_gather<0, false><<<gNode4, 256, 0, stream>>>(rowptr, colidx, HWb, in, dinv, bl, nullptr, outb);
    }
    // conv output in A

    // ---- post-processing ----
    k_gemm<0, true, false, true, false><<<GEMM_BLK, 256, 0, stream>>>(A, post_W, post_b, nullptr, nullptr, C, partial, N_NODES);
    k_statsfin<<<64, 256, 0, stream>>>(partial, post_g, post_beta, scsh + 3 * 128, N_NODES);

    k_gemm<2, true, false, true, false><<<GEMM_BLK, 256, 0, stream>>>(C, post_W + 4096, post_b + 64, nullptr, scsh + 3 * 128, A, partial, N_NODES);
    k_statsfin<<<64, 256, 0, stream>>>(partial, post_g + 64, post_beta + 64, scsh + 4 * 128, N_NODES);

    k_gemm<2, true, false, true, false><<<GEMM_BLK, 256, 0, stream>>>(A, post_W + 2 * 4096, post_b + 128, nullptr, scsh + 4 * 128, C, partial, N_NODES);
    k_statsfin<<<64, 256, 0, stream>>>(partial, post_g + 128, post_beta + 128, scsh + 5 * 128, N_NODES);

    // ---- pool (two-stage segment mean, fused final BN) + head ----
    k_pool1<<<NGRAPH * POOL_SUB, 256, 0, stream>>>(C, batch, partial2);
    k_pool2<<<NGRAPH, 64, 0, stream>>>(partial2, batch, scsh + 5 * 128, pooled);
    k_final<<<1, 256, 0, stream>>>(pooled, fW0, fb0, fW1, fb1, fW2, fb2, out);
}

// Round 6
// 571.100 us; speedup vs baseline: 2.2151x; 1.1722x over previous
//
#include <hip/hip_runtime.h>

#define N_NODES 100000
#define N_EDGES 800000
#define HID 64
#define NGRAPH 64
#define OUTC 2
#define BN_EPS 1e-5f
#define NSCAN_BLK ((N_NODES + 255) / 256)   // 391
#define GEMM_BLK ((N_NODES + 63) / 64)      // 1563
#define POOL_SUB 16

typedef __attribute__((ext_vector_type(8))) short bf16x8;
typedef __attribute__((ext_vector_type(4))) float f32x4;

__device__ __forceinline__ unsigned short f2bf(float f) {
    unsigned int u = __float_as_uint(f);
    u = (u + 0x7FFFu + ((u >> 16) & 1u)) >> 16;   // round-to-nearest-even
    return (unsigned short)u;
}

// ---------------------------------------------------------------------------
// GEMM via bf16 MFMA: Y[n,64] = T(X)[n,64] @ W[64,64] (+bias) (opt dinv row-scale)
// T(X) = optional per-column BN (scale/shift) + optional ReLU, fp32, fused on
// load, then RNE-converted to bf16. MFMA 16x16x32, fp32 accumulate.
// A/B fragments are loaded with the SAME (lane-kgroup, reg)->k convention for
// both operands, so the exact HW k-layout is irrelevant (slot-paired k-sum);
// C/D layout is the HW-verified col=lane&15, row=(lane>>4)*4+reg.
// IN_MODE: 0 = identity, 1 = BN, 2 = BN + ReLU
// STATS: per-block column sum/sumsq partials via shfl reduce.
// OUT_BF16: write Y as bf16 (conv HW buffer; halves gather fetch traffic).
// ---------------------------------------------------------------------------
template <int IN_MODE, bool ADD_BIAS, bool ROW_SCALE, bool STATS, bool OUT_BF16>
__global__ __launch_bounds__(256) void k_gemm(const float* __restrict__ X,
                                              const float* __restrict__ W,
                                              const float* __restrict__ bias,
                                              const float* __restrict__ dinv,
                                              const float* __restrict__ scsh,
                                              void* __restrict__ Yv,
                                              float* __restrict__ partial, int n) {
    __shared__ __align__(16) unsigned short sXb[64][72];  // bf16 X tile (pad 72)
    __shared__ __align__(16) unsigned short sWT[64][72];  // bf16 W^T: sWT[c][k]
    __shared__ float sDinv[64];
    const int tid  = threadIdx.x;
    const int row0 = blockIdx.x * 64;

    // stage W^T (bf16): sWT[c][k] = W[k][c]
    #pragma unroll
    for (int i = tid; i < 1024; i += 256) {
        int k = i >> 4, c4 = (i & 15) << 2;
        float4 w = *reinterpret_cast<const float4*>(&W[k * 64 + c4]);
        sWT[c4 + 0][k] = f2bf(w.x);
        sWT[c4 + 1][k] = f2bf(w.y);
        sWT[c4 + 2][k] = f2bf(w.z);
        sWT[c4 + 3][k] = f2bf(w.w);
    }
    // stage X tile (64x64) with fused fp32 BN/ReLU transform, cvt to bf16
    #pragma unroll
    for (int f = tid; f < 1024; f += 256) {
        int r = f >> 4, c4 = (f & 15) << 2;
        float4 v = make_float4(0.f, 0.f, 0.f, 0.f);
        if (row0 + r < n)
            v = *reinterpret_cast<const float4*>(&X[(size_t)(row0 + r) * HID + c4]);
        if (IN_MODE >= 1) {
            float4 sc = *reinterpret_cast<const float4*>(&scsh[c4]);
            float4 sh = *reinterpret_cast<const float4*>(&scsh[64 + c4]);
            v.x = v.x * sc.x + sh.x; v.y = v.y * sc.y + sh.y;
            v.z = v.z * sc.z + sh.z; v.w = v.w * sc.w + sh.w;
            if (IN_MODE == 2) {
                v.x = fmaxf(v.x, 0.f); v.y = fmaxf(v.y, 0.f);
                v.z = fmaxf(v.z, 0.f); v.w = fmaxf(v.w, 0.f);
            }
        }
        sXb[r][c4 + 0] = f2bf(v.x);
        sXb[r][c4 + 1] = f2bf(v.y);
        sXb[r][c4 + 2] = f2bf(v.z);
        sXb[r][c4 + 3] = f2bf(v.w);
    }
    if (ROW_SCALE && tid < 64)
        sDinv[tid] = (row0 + tid < n) ? dinv[row0 + tid] : 0.f;
    __syncthreads();

    const int lane = tid & 63;
    const int wv   = tid >> 6;          // wave id -> col tile wv*16..+15
    const int cl   = lane & 15;         // col within tile
    const int kg   = lane >> 4;         // k-group 0..3
    const int col  = (wv << 4) + cl;    // column in 64-wide tile

    const f32x4 zero = {0.f, 0.f, 0.f, 0.f};
    f32x4 acc[4];
    #pragma unroll
    for (int m = 0; m < 4; ++m) acc[m] = zero;

    #pragma unroll
    for (int k0 = 0; k0 < 64; k0 += 32) {
        bf16x8 bfrag = *reinterpret_cast<const bf16x8*>(&sWT[col][k0 + (kg << 3)]);
        #pragma unroll
        for (int m = 0; m < 4; ++m) {
            bf16x8 afrag = *reinterpret_cast<const bf16x8*>(&sXb[(m << 4) + cl][k0 + (kg << 3)]);
            acc[m] = __builtin_amdgcn_mfma_f32_16x16x32_bf16(afrag, bfrag, acc[m], 0, 0, 0);
        }
    }

    const float bb = ADD_BIAS ? bias[col] : 0.f;
    float colS = 0.f, colQ = 0.f;
    #pragma unroll
    for (int m = 0; m < 4; ++m) {
        #pragma unroll
        for (int j = 0; j < 4; ++j) {
            int rl = (m << 4) + (kg << 2) + j;   // C/D: row=(lane>>4)*4+reg
            int r  = row0 + rl;
            if (r < n) {
                float s = ROW_SCALE ? sDinv[rl] : 1.f;
                float o = acc[m][j] * s + bb;
                if (OUT_BF16)
                    ((unsigned short*)Yv)[(size_t)r * HID + col] = f2bf(o);
                else
                    ((float*)Yv)[(size_t)r * HID + col] = o;
                if (STATS) { colS += o; colQ += o * o; }
            }
        }
    }
    if (STATS) {
        colS += __shfl_xor(colS, 16); colQ += __shfl_xor(colQ, 16);
        colS += __shfl_xor(colS, 32); colQ += __shfl_xor(colQ, 32);
        if (kg == 0) {
            partial[blockIdx.x * 128 + col]      = colS;
            partial[blockIdx.x * 128 + 64 + col] = colQ;
        }
    }
}

// Reduce per-block partials -> scale/shift. One block per column.
__global__ __launch_bounds__(256) void k_statsfin(const float* __restrict__ partial,
                                                  const float* __restrict__ g,
                                                  const float* __restrict__ beta,
                                                  float* __restrict__ scsh, int n) {
    int c = blockIdx.x, t = threadIdx.x;
    float S = 0.f, Q = 0.f;
    for (int b = t; b < GEMM_BLK; b += 256) {
        S += partial[b * 128 + c];
        Q += partial[b * 128 + 64 + c];
    }
    __shared__ float ss[256], sq[256];
    ss[t] = S; sq[t] = Q;
    __syncthreads();
    for (int off = 128; off > 0; off >>= 1) {
        if (t < off) { ss[t] += ss[t + off]; sq[t] += sq[t + off]; }
        __syncthreads();
    }
    if (t == 0) {
        float nf = (float)n;
        float m  = ss[0] / nf;
        float v  = sq[0] / nf - m * m;
        float sc = rsqrtf(v + BN_EPS) * g[c];
        scsh[c]      = sc;
        scsh[64 + c] = beta[c] - m * sc;
    }
}

// ---------------------------------------------------------------------------
// CSR build
// ---------------------------------------------------------------------------
__global__ __launch_bounds__(256) void k_deg(const int* __restrict__ dst,
                                             int* __restrict__ indeg) {
    int e = blockIdx.x * 256 + threadIdx.x;
    if (e < N_EDGES) atomicAdd(&indeg[dst[e]], 1);
}

__global__ __launch_bounds__(256) void k_scanpart(const int* __restrict__ indeg,
                                                  int* __restrict__ bsum) {
    __shared__ int s[256];
    int i = blockIdx.x * 256 + threadIdx.x;
    s[threadIdx.x] = (i < N_NODES) ? indeg[i] : 0;
    __syncthreads();
    for (int off = 128; off > 0; off >>= 1) {
        if (threadIdx.x < off) s[threadIdx.x] += s[threadIdx.x + off];
        __syncthreads();
    }
    if (threadIdx.x == 0) bsum[blockIdx.x] = s[0];
}

__global__ __launch_bounds__(512) void k_scanmid(int* __restrict__ bsum, int nblk) {
    __shared__ int s[512];
    int t = threadIdx.x;
    int v = (t < nblk) ? bsum[t] : 0;
    s[t] = v;
    __syncthreads();
    for (int off = 1; off < 512; off <<= 1) {
        int x = (t >= off) ? s[t - off] : 0;
        __syncthreads();
        s[t] += x;
        __syncthreads();
    }
    if (t < nblk) bsum[t] = s[t] - v;   // exclusive
}

__global__ __launch_bounds__(256) void k_scanfinal(const int* __restrict__ indeg,
                                                   const int* __restrict__ bsum,
                                                   int* __restrict__ rowptr) {
    __shared__ int s[256];
    int t = threadIdx.x;
    int i = blockIdx.x * 256 + t;
    int v = (i < N_NODES) ? indeg[i] : 0;
    s[t] = v;
    __syncthreads();
    for (int off = 1; off < 256; off <<= 1) {
        int x = (t >= off) ? s[t - off] : 0;
        __syncthreads();
        s[t] += x;
        __syncthreads();
    }
    if (i < N_NODES) rowptr[i] = bsum[blockIdx.x] + s[t] - v;
    if (i == 0) rowptr[N_NODES] = N_EDGES;
}

__global__ __launch_bounds__(256) void k_dinv(const int* __restrict__ indeg,
                                              float* __restrict__ dinv) {
    int i = blockIdx.x * 256 + threadIdx.x;
    if (i < N_NODES) dinv[i] = rsqrtf((float)indeg[i] + 1.f);
}

__global__ __launch_bounds__(256) void k_fill(const int* __restrict__ src,
                                              const int* __restrict__ dst,
                                              const int* __restrict__ rowptr,
                                              int* __restrict__ indeg,
                                              int* __restrict__ colidx) {
    int e = blockIdx.x * 256 + threadIdx.x;
    if (e >= N_EDGES) return;
    int d = dst[e];
    int pos = rowptr[d] + (atomicSub(&indeg[d], 1) - 1);
    colidx[pos] = src[e];
}

// ---------------------------------------------------------------------------
// Fused gather + conv finalize: one wave per dst node, 8 edge-slots x 8
// col-lanes x bf16x8 (16B/lane). HW rows are bf16; accumulation fp32.
// ---------------------------------------------------------------------------
template <int IN_MODE, bool RELU>
__global__ __launch_bounds__(256) void k_gather(const int* __restrict__ rowptr,
                                                const int* __restrict__ colidx,
                                                const unsigned short* __restrict__ HWb,
                                                const float* __restrict__ Hin,
                                                const float* __restrict__ dinv,
                                                const float* __restrict__ bias,
                                                const float* __restrict__ scsh,
                                                float* __restrict__ Out) {
    int d = blockIdx.x * 4 + (threadIdx.x >> 6);
    if (d >= N_NODES) return;
    const int lane = threadIdx.x & 63;
    const int slot = lane >> 3;          // 0..7 edge slot
    const int c8   = (lane & 7) << 3;    // column base (8 cols per lane)
    const int j0 = rowptr[d], j1 = rowptr[d + 1];

    float acc[8];
    #pragma unroll
    for (int k = 0; k < 8; ++k) acc[k] = 0.f;

    if (slot == 7) {  // self-loop term
        uint4 v = *reinterpret_cast<const uint4*>(&HWb[(size_t)d * HID + c8]);
        acc[0] += __uint_as_float(v.x << 16);
        acc[1] += __uint_as_float(v.x & 0xFFFF0000u);
        acc[2] += __uint_as_float(v.y << 16);
        acc[3] += __uint_as_float(v.y & 0xFFFF0000u);
        acc[4] += __uint_as_float(v.z << 16);
        acc[5] += __uint_as_float(v.z & 0xFFFF0000u);
        acc[6] += __uint_as_float(v.w << 16);
        acc[7] += __uint_as_float(v.w & 0xFFFF0000u);
    }
    for (int j = j0 + slot; j < j1; j += 8) {
        int s = colidx[j];
        uint4 v = *reinterpret_cast<const uint4*>(&HWb[(size_t)s * HID + c8]);
        acc[0] += __uint_as_float(v.x << 16);
        acc[1] += __uint_as_float(v.x & 0xFFFF0000u);
        acc[2] += __uint_as_float(v.y << 16);
        acc[3] += __uint_as_float(v.y & 0xFFFF0000u);
        acc[4] += __uint_as_float(v.z << 16);
        acc[5] += __uint_as_float(v.z & 0xFFFF0000u);
        acc[6] += __uint_as_float(v.w << 16);
        acc[7] += __uint_as_float(v.w & 0xFFFF0000u);
    }
    // reduce across the 8 slots (lane bits 3,4,5)
    #pragma unroll
    for (int m = 8; m < 64; m <<= 1) {
        #pragma unroll
        for (int k = 0; k < 8; ++k) acc[k] += __shfl_xor(acc[k], m);
    }

    if (slot == 0) {
        float4 h0 = *reinterpret_cast<const float4*>(&Hin[(size_t)d * HID + c8]);
        float4 h1 = *reinterpret_cast<const float4*>(&Hin[(size_t)d * HID + c8 + 4]);
        if (IN_MODE == 1) {
            float4 sc0 = *reinterpret_cast<const float4*>(&scsh[c8]);
            float4 sc1 = *reinterpret_cast<const float4*>(&scsh[c8 + 4]);
            float4 sh0 = *reinterpret_cast<const float4*>(&scsh[64 + c8]);
            float4 sh1 = *reinterpret_cast<const float4*>(&scsh[64 + c8 + 4]);
            h0.x = h0.x * sc0.x + sh0.x; h0.y = h0.y * sc0.y + sh0.y;
            h0.z = h0.z * sc0.z + sh0.z; h0.w = h0.w * sc0.w + sh0.w;
            h1.x = h1.x * sc1.x + sh1.x; h1.y = h1.y * sc1.y + sh1.y;
            h1.z = h1.z * sc1.z + sh1.z; h1.w = h1.w * sc1.w + sh1.w;
        }
        float di = dinv[d];
        float4 b0 = *reinterpret_cast<const float4*>(&bias[c8]);
        float4 b1 = *reinterpret_cast<const float4*>(&bias[c8 + 4]);
        float4 o0, o1;
        o0.x = acc[0] * di + b0.x + h0.x;
        o0.y = acc[1] * di + b0.y + h0.y;
        o0.z = acc[2] * di + b0.z + h0.z;
        o0.w = acc[3] * di + b0.w + h0.w;
        o1.x = acc[4] * di + b1.x + h1.x;
        o1.y = acc[5] * di + b1.y + h1.y;
        o1.z = acc[6] * di + b1.z + h1.z;
        o1.w = acc[7] * di + b1.w + h1.w;
        if (RELU) {
            o0.x = fmaxf(o0.x, 0.f); o0.y = fmaxf(o0.y, 0.f);
            o0.z = fmaxf(o0.z, 0.f); o0.w = fmaxf(o0.w, 0.f);
            o1.x = fmaxf(o1.x, 0.f); o1.y = fmaxf(o1.y, 0.f);
            o1.z = fmaxf(o1.z, 0.f); o1.w = fmaxf(o1.w, 0.f);
        }
        *reinterpret_cast<float4*>(&Out[(size_t)d * HID + c8])     = o0;
        *reinterpret_cast<float4*>(&Out[(size_t)d * HID + c8 + 4]) = o1;
    }
}

// ---------------------------------------------------------------------------
// Two-stage segment-mean pool over sorted batch + fused final BN
// ---------------------------------------------------------------------------
__device__ __forceinline__ int lowerb(const int* __restrict__ b, int n, int v) {
    int lo = 0, hi = n;
    while (lo < hi) { int m = (lo + hi) >> 1; if (b[m] < v) lo = m + 1; else hi = m; }
    return lo;
}

__global__ __launch_bounds__(256) void k_pool1(const float* __restrict__ Y,
                                               const int* __restrict__ batch,
                                               float* __restrict__ partial2) {
    int g  = blockIdx.x >> 4;
    int sb = blockIdx.x & 15;
    int tid = threadIdx.x, col = tid & 63, rg = tid >> 6;
    int lo = lowerb(batch, N_NODES, g);
    int hi = lowerb(batch, N_NODES, g + 1);
    int cnt = hi - lo;
    int st = lo + (int)(((long long)cnt * sb) >> 4);
    int en = lo + (int)(((long long)cnt * (sb + 1)) >> 4);
    float s = 0.f;
    for (int r = st + rg; r < en; r += 4) s += Y[(size_t)r * HID + col];
    __shared__ float ls[4][64];
    ls[rg][col] = s;
    __syncthreads();
    if (tid < 64)
        partial2[(size_t)blockIdx.x * 64 + tid] =
            ls[0][tid] + ls[1][tid] + ls[2][tid] + ls[3][tid];
}

__global__ __launch_bounds__(64) void k_pool2(const float* __restrict__ partial2,
                                              const int* __restrict__ batch,
                                              const float* __restrict__ scsh,
                                              float* __restrict__ pooled) {
    int g = blockIdx.x, c = threadIdx.x;
    float S = 0.f;
    #pragma unroll
    for (int sb = 0; sb < POOL_SUB; ++sb)
        S += partial2[(size_t)(g * POOL_SUB + sb) * 64 + c];
    int lo = lowerb(batch, N_NODES, g);
    int hi = lowerb(batch, N_NODES, g + 1);
    int cnt = hi - lo;
    float out = 0.f;
    if (cnt > 0) {
        float mean = S / (float)cnt;
        out = mean * scsh[c] + scsh[64 + c];
    }
    pooled[g * 64 + c] = out;
}

// ---------------------------------------------------------------------------
// Final head
// ---------------------------------------------------------------------------
__global__ __launch_bounds__(256) void k_final(const float* __restrict__ pooled,
                                               const float* __restrict__ W0,
                                               const float* __restrict__ b0,
                                               const float* __restrict__ W1,
                                               const float* __restrict__ b1,
                                               const float* __restrict__ W2,
                                               const float* __restrict__ b2,
                                               float* __restrict__ out) {
    __shared__ float P[64][65];
    __shared__ float Z[64][65];
    int tid = threadIdx.x;
    for (int i = tid; i < NGRAPH * HID; i += 256) P[i >> 6][i & 63] = pooled[i];
    __syncthreads();
    for (int t = 0; t < 16; ++t) {
        int o = tid + 256 * t; int r = o >> 6, c = o & 63;
        float acc = b0[c];
        #pragma unroll 8
        for (int k = 0; k < 64; ++k) acc += P[r][k] * W0[k * 64 + c];
        Z[r][c] = fmaxf(acc, 0.f);
    }
    __syncthreads();
    for (int t = 0; t < 16; ++t) {
        int o = tid + 256 * t; int r = o >> 6, c = o & 63;
        float acc = b1[c];
        #pragma unroll 8
        for (int k = 0; k < 64; ++k) acc += Z[r][k] * W1[k * 64 + c];
        P[r][c] = fmaxf(acc, 0.f);
    }
    __syncthreads();
    if (tid < NGRAPH * OUTC) {
        int r = tid >> 1, c = tid & 1;
        float acc = b2[c];
        #pragma unroll 8
        for (int k = 0; k < 64; ++k) acc += P[r][k] * W2[k * OUTC + c];
        out[tid] = acc;
    }
}

// ---------------------------------------------------------------------------
extern "C" void kernel_launch(void* const* d_in, const int* in_sizes, int n_in,
                              void* d_out, int out_size, void* d_ws, size_t ws_size,
                              hipStream_t stream) {
    const float* x        = (const float*)d_in[0];
    const int*   ei       = (const int*)d_in[1];
    const int*   batch    = (const int*)d_in[2];
    const float* pre_W    = (const float*)d_in[3];
    const float* pre_b    = (const float*)d_in[4];
    const float* pre_g    = (const float*)d_in[5];
    const float* pre_beta = (const float*)d_in[6];
    const float* conv_W   = (const float*)d_in[7];
    const float* conv_b   = (const float*)d_in[8];
    const float* post_W   = (const float*)d_in[9];
    const float* post_b   = (const float*)d_in[10];
    const float* post_g   = (const float*)d_in[11];
    const float* post_beta= (const float*)d_in[12];
    const float* fW0 = (const float*)d_in[13];
    const float* fb0 = (const float*)d_in[14];
    const float* fW1 = (const float*)d_in[15];
    const float* fb1 = (const float*)d_in[16];
    const float* fW2 = (const float*)d_in[17];
    const float* fb2 = (const float*)d_in[18];
    float* out = (float*)d_out;

    const size_t NH = (size_t)N_NODES * HID;
    float* ws       = (float*)d_ws;
    float* A        = ws;
    float* B        = A + NH;          // bf16 HW buffer lives here (NH ushorts)
    float* C        = B + NH;
    float* dinv     = C + NH;                         // N
    float* partial  = dinv + N_NODES;                 // GEMM_BLK*128
    float* scsh     = partial + (size_t)GEMM_BLK*128; // 6 slots of 128
    float* pooled   = scsh + 6 * 128;                 // 64*64
    float* partial2 = pooled + NGRAPH * HID;          // 1024*64
    int*   indeg    = (int*)(partial2 + NGRAPH * POOL_SUB * 64);
    int*   rowptr   = indeg + N_NODES;                // N+1
    int*   colidx   = rowptr + N_NODES + 1;           // E
    int*   bsum     = colidx + N_EDGES;               // NSCAN_BLK
    unsigned short* HWb = (unsigned short*)B;

    const int* srcp = ei;
    const int* dstp = ei + N_EDGES;

    const int gEdge  = (N_EDGES + 255) / 256;
    const int gNode  = (N_NODES + 255) / 256;
    const int gNode4 = (N_NODES + 3) / 4;

    // ---- CSR build ----
    hipMemsetAsync(indeg, 0, N_NODES * sizeof(int), stream);
    k_deg<<<gEdge, 256, 0, stream>>>(dstp, indeg);
    k_scanpart<<<NSCAN_BLK, 256, 0, stream>>>(indeg, bsum);
    k_scanmid<<<1, 512, 0, stream>>>(bsum, NSCAN_BLK);
    k_scanfinal<<<NSCAN_BLK, 256, 0, stream>>>(indeg, bsum, rowptr);
    k_dinv<<<gNode, 256, 0, stream>>>(indeg, dinv);
    k_fill<<<gEdge, 256, 0, stream>>>(srcp, dstp, rowptr, indeg, colidx);

    // ---- pre-processing: GEMM(+fused prev BN/ReLU, +stats) ----
    k_gemm<0, true, false, true, false><<<GEMM_BLK, 256, 0, stream>>>(x, pre_W, pre_b, nullptr, nullptr, A, partial, N_NODES);
    k_statsfin<<<64, 256, 0, stream>>>(partial, pre_g, pre_beta, scsh + 0 * 128, N_NODES);

    k_gemm<2, true, false, true, false><<<GEMM_BLK, 256, 0, stream>>>(A, pre_W + 4096, pre_b + 64, nullptr, scsh + 0 * 128, (float*)(C), partial, N_NODES);
    k_statsfin<<<64, 256, 0, stream>>>(partial, pre_g + 64, pre_beta + 64, scsh + 1 * 128, N_NODES);

    k_gemm<2, true, false, true, false><<<GEMM_BLK, 256, 0, stream>>>(C, pre_W + 2 * 4096, pre_b + 128, nullptr, scsh + 1 * 128, A, partial, N_NODES);
    k_statsfin<<<64, 256, 0, stream>>>(partial, pre_g + 128, pre_beta + 128, scsh + 2 * 128, N_NODES);

    // ---- GCNConv stack (HW in bf16) ----
    for (int i = 0; i < 6; ++i) {
        const float* in = (i & 1) ? C : A;
        float*     outb = (i & 1) ? A : C;
        const float* Wl = conv_W + i * 4096;
        const float* bl = conv_b + i * 64;
        if (i == 0)
            k_gemm<1, false, true, false, true><<<GEMM_BLK, 256, 0, stream>>>(in, Wl, nullptr, dinv, scsh + 2 * 128, HWb, nullptr, N_NODES);
        else
            k_gemm<0, false, true, false, true><<<GEMM_BLK, 256, 0, stream>>>(in, Wl, nullptr, dinv, nullptr, HWb, nullptr, N_NODES);

        if (i == 0)
            k_gather<1, true ><<<gNode4, 256, 0, stream>>>(rowptr, colidx, HWb, in, dinv, bl, scsh + 2 * 128, outb);
        else if (i != 5)
            k_gather<0, true ><<<gNode4, 256, 0, stream>>>(rowptr, colidx, HWb, in, dinv, bl, nullptr, outb);
        else
            k_gather<0, false><<<gNode4, 256, 0, stream>>>(rowptr, colidx, HWb, in, dinv, bl, nullptr, outb);
    }
    // conv output in A

    // ---- post-processing ----
    k_gemm<0, true, false, true, false><<<GEMM_BLK, 256, 0, stream>>>(A, post_W, post_b, nullptr, nullptr, C, partial, N_NODES);
    k_statsfin<<<64, 256, 0, stream>>>(partial, post_g, post_beta, scsh + 3 * 128, N_NODES);

    k_gemm<2, true, false, true, false><<<GEMM_BLK, 256, 0, stream>>>(C, post_W + 4096, post_b + 64, nullptr, scsh + 3 * 128, A, partial, N_NODES);
    k_statsfin<<<64, 256, 0, stream>>>(partial, post_g + 64, post_beta + 64, scsh + 4 * 128, N_NODES);

    k_gemm<2, true, false, true, false><<<GEMM_BLK, 256, 0, stream>>>(A, post_W + 2 * 4096, post_b + 128, nullptr, scsh + 4 * 128, C, partial, N_NODES);
    k_statsfin<<<64, 256, 0, stream>>>(partial, post_g + 128, post_beta + 128, scsh + 5 * 128, N_NODES);

    // ---- pool (two-stage segment mean, fused final BN) + head ----
    k_pool1<<<NGRAPH * POOL_SUB, 256, 0, stream>>>(C, batch, partial2);
    k_pool2<<<NGRAPH, 64, 0, stream>>>(partial2, batch, scsh + 5 * 128, pooled);
    k_final<<<1, 256, 0, stream>>>(pooled, fW0, fb0, fW1, fb1, fW2, fb2, out);
}